// Round 1
// baseline (930.693 us; speedup 1.0000x reference)
//
#include <hip/hip_runtime.h>
#include <hip/hip_bf16.h>

#define DEVI __device__ __forceinline__

typedef __attribute__((ext_vector_type(8))) short short8;
typedef __attribute__((ext_vector_type(4))) float f32x4;
typedef __attribute__((ext_vector_type(4))) unsigned short us4;

constexpr int Bb = 2, Ss = 1024, Dd = 2048, Hh = 16, KVv = 8, HDd = 128;

constexpr int BM = 128, BN = 128, BK = 32, BKP = 40;

DEVI unsigned short bfbits(float x) {
    union { __hip_bfloat16 b; unsigned short u; } cv;
    cv.b = __float2bfloat16(x);
    return cv.u;
}
DEVI float bff(unsigned short u) {
    union { unsigned short u; __hip_bfloat16 b; } cv;
    cv.u = u;
    return __bfloat162float(cv.b);
}

// C = A (M x K, row-major, fp32) * B^T (B is N x K row-major, fp32), fp32 out.
// Split-bf16 (hi+lo) with 3 MFMAs per fragment pair for ~1e-5 relative error.
// Batched via blockIdx.z with flexible per-operand offsets:
//   zo = z / zdiv, zi = z % zdiv; ptr += zo*of0 + (zi/div)*of1
__global__ __launch_bounds__(256) void gemm3(
    const float* __restrict__ A, const float* __restrict__ B, float* __restrict__ C,
    int lda, int ldb, int ldc, int K,
    long aof0, long aof1, int adiv,
    long bof0, long bof1, int bdiv,
    long cof0, long cof1, int cdiv,
    int zdiv)
{
    const int z = blockIdx.z;
    const int zo = z / zdiv, zi = z - zo * zdiv;
    A += (long)zo * aof0 + (long)(zi / adiv) * aof1;
    B += (long)zo * bof0 + (long)(zi / bdiv) * bof1;
    C += (long)zo * cof0 + (long)(zi / cdiv) * cof1;
    const int m0 = blockIdx.y * BM, n0 = blockIdx.x * BN;

    __shared__ unsigned short Ah[BM][BKP], Al[BM][BKP], Bh[BN][BKP], Bl[BN][BKP];

    const int tid = threadIdx.x;
    const int wave = tid >> 6, lane = tid & 63;
    const int wr = (wave >> 1) * 64, wc = (wave & 1) * 64;
    const int frow = lane & 15, fk = (lane >> 4) * 8;

    f32x4 acc[4][4] = {};

    for (int k0 = 0; k0 < K; k0 += BK) {
        // stage 128x32 fp32 of A and B each; split to bf16 hi/lo in LDS
#pragma unroll
        for (int it = 0; it < 4; ++it) {
            int idx = it * 256 + tid;
            int r = idx >> 3, c4 = (idx & 7) << 2;
            float4 va = *reinterpret_cast<const float4*>(&A[(long)(m0 + r) * lda + k0 + c4]);
            float4 vb = *reinterpret_cast<const float4*>(&B[(long)(n0 + r) * ldb + k0 + c4]);
            float fa[4] = {va.x, va.y, va.z, va.w};
            float fb[4] = {vb.x, vb.y, vb.z, vb.w};
            us4 ah, al, bh, bl;
#pragma unroll
            for (int j = 0; j < 4; ++j) {
                unsigned short h = bfbits(fa[j]);
                ah[j] = h; al[j] = bfbits(fa[j] - bff(h));
                unsigned short g = bfbits(fb[j]);
                bh[j] = g; bl[j] = bfbits(fb[j] - bff(g));
            }
            *reinterpret_cast<us4*>(&Ah[r][c4]) = ah;
            *reinterpret_cast<us4*>(&Al[r][c4]) = al;
            *reinterpret_cast<us4*>(&Bh[r][c4]) = bh;
            *reinterpret_cast<us4*>(&Bl[r][c4]) = bl;
        }
        __syncthreads();

        short8 a_h[4], a_l[4], b_h[4], b_l[4];
#pragma unroll
        for (int m = 0; m < 4; ++m) {
            a_h[m] = *reinterpret_cast<const short8*>(&Ah[wr + m * 16 + frow][fk]);
            a_l[m] = *reinterpret_cast<const short8*>(&Al[wr + m * 16 + frow][fk]);
            b_h[m] = *reinterpret_cast<const short8*>(&Bh[wc + m * 16 + frow][fk]);
            b_l[m] = *reinterpret_cast<const short8*>(&Bl[wc + m * 16 + frow][fk]);
        }
#pragma unroll
        for (int m = 0; m < 4; ++m)
#pragma unroll
            for (int n = 0; n < 4; ++n) {
                acc[m][n] = __builtin_amdgcn_mfma_f32_16x16x32_bf16(a_h[m], b_h[n], acc[m][n], 0, 0, 0);
                acc[m][n] = __builtin_amdgcn_mfma_f32_16x16x32_bf16(a_h[m], b_l[n], acc[m][n], 0, 0, 0);
                acc[m][n] = __builtin_amdgcn_mfma_f32_16x16x32_bf16(a_l[m], b_h[n], acc[m][n], 0, 0, 0);
            }
        __syncthreads();
    }

#pragma unroll
    for (int m = 0; m < 4; ++m)
#pragma unroll
        for (int n = 0; n < 4; ++n)
#pragma unroll
            for (int j = 0; j < 4; ++j) {
                long row = m0 + wr + m * 16 + (lane >> 4) * 4 + j;
                int col = n0 + wc + n * 16 + (lane & 15);
                C[row * (long)ldc + col] = acc[m][n][j];
            }
}

// Per (b,s): RMSNorm over HD per head + RoPE for q,k; write q->state (B,H,S,HD),
// k->kbuf (B,KV,S,HD) and kT (B,KV,HD,S); v->vT (B,KV,HD,S).
__global__ __launch_bounds__(256) void qkv_epi(
    const float* __restrict__ qkv, const float* __restrict__ cosb, const float* __restrict__ sinb,
    const float* __restrict__ qw, const float* __restrict__ kw,
    float* __restrict__ state, float* __restrict__ kbuf,
    float* __restrict__ kT, float* __restrict__ vT)
{
    const int bs = blockIdx.x;
    const int b = bs >> 10, s = bs & 1023;
    const float* row = qkv + (long)bs * 4096;
    const int wave = threadIdx.x >> 6, lane = threadIdx.x & 63;
    const float* cp = cosb + (long)bs * 128;
    const float* sp = sinb + (long)bs * 128;
    const float clo = cp[lane], chi = cp[lane + 64];
    const float slo = sp[lane], shi = sp[lane + 64];

    for (int h = wave; h < Hh; h += 4) {
        float xlo = row[h * 128 + lane], xhi = row[h * 128 + 64 + lane];
        float ss = xlo * xlo + xhi * xhi;
#pragma unroll
        for (int o = 32; o; o >>= 1) ss += __shfl_xor(ss, o);
        float r = 1.0f / sqrtf(ss * (1.0f / 128.0f) + 1e-6f);
        float ylo = xlo * r * qw[lane], yhi = xhi * r * qw[lane + 64];
        float olo = ylo * clo - yhi * slo;
        float ohi = yhi * chi + ylo * shi;
        float* dst = state + (((long)b * Hh + h) * Ss + s) * 128;
        dst[lane] = olo; dst[lane + 64] = ohi;
    }
    for (int kv = wave; kv < KVv; kv += 4) {
        float xlo = row[2048 + kv * 128 + lane], xhi = row[2048 + kv * 128 + 64 + lane];
        float ss = xlo * xlo + xhi * xhi;
#pragma unroll
        for (int o = 32; o; o >>= 1) ss += __shfl_xor(ss, o);
        float r = 1.0f / sqrtf(ss * (1.0f / 128.0f) + 1e-6f);
        float ylo = xlo * r * kw[lane], yhi = xhi * r * kw[lane + 64];
        float olo = ylo * clo - yhi * slo;
        float ohi = yhi * chi + ylo * shi;
        long base = (long)b * KVv + kv;
        float* dst = kbuf + (base * Ss + s) * 128;
        dst[lane] = olo; dst[lane + 64] = ohi;
        float* dT = kT + base * 128 * Ss;
        dT[(long)lane * Ss + s] = olo;
        dT[(long)(lane + 64) * Ss + s] = ohi;
    }
    for (int kv = wave; kv < KVv; kv += 4) {
        float xlo = row[3072 + kv * 128 + lane], xhi = row[3072 + kv * 128 + 64 + lane];
        long base = (long)b * KVv + kv;
        float* dT = vT + base * 128 * Ss;
        dT[(long)lane * Ss + s] = xlo;
        dT[(long)(lane + 64) * Ss + s] = xhi;
    }
}

// In-place causal softmax over one row of the (Z=32, S, S) score buffer.
// scores were raw dots; apply scale*exp(log_beta) and mask j>i with -1e9.
__global__ __launch_bounds__(256) void softmax_causal(
    float* __restrict__ scores, const float* __restrict__ log_beta)
{
    const int row = blockIdx.x;
    const long z = blockIdx.y;
    float* rp = scores + (z * Ss + row) * (long)Ss;
    const int tid = threadIdx.x;
    const int wave = tid >> 6, lane = tid & 63;
    const float sb = 0.08838834764831845f * expf(log_beta[0]);

    float4 v = reinterpret_cast<float4*>(rp)[tid];
    const int c0 = tid * 4;
    float x0 = v.x * sb + (c0 + 0 <= row ? 0.f : -1e9f);
    float x1 = v.y * sb + (c0 + 1 <= row ? 0.f : -1e9f);
    float x2 = v.z * sb + (c0 + 2 <= row ? 0.f : -1e9f);
    float x3 = v.w * sb + (c0 + 3 <= row ? 0.f : -1e9f);

    __shared__ float red[8];
    float mx = fmaxf(fmaxf(x0, x1), fmaxf(x2, x3));
#pragma unroll
    for (int o = 32; o; o >>= 1) mx = fmaxf(mx, __shfl_xor(mx, o));
    if (lane == 0) red[wave] = mx;
    __syncthreads();
    mx = fmaxf(fmaxf(red[0], red[1]), fmaxf(red[2], red[3]));

    float e0 = expf(x0 - mx), e1 = expf(x1 - mx), e2 = expf(x2 - mx), e3 = expf(x3 - mx);
    float sm = e0 + e1 + e2 + e3;
#pragma unroll
    for (int o = 32; o; o >>= 1) sm += __shfl_xor(sm, o);
    if (lane == 0) red[4 + wave] = sm;
    __syncthreads();
    sm = red[4] + red[5] + red[6] + red[7];
    float inv = 1.0f / sm;

    float4 o4;
    o4.x = e0 * inv; o4.y = e1 * inv; o4.z = e2 * inv; o4.w = e3 * inv;
    reinterpret_cast<float4*>(rp)[tid] = o4;
}

static inline void launch_gemm(hipStream_t st, const float* A, const float* B, float* C,
                               int M, int N, int lda, int ldb, int ldc, int K, int Z,
                               long aof0, long aof1, int adiv,
                               long bof0, long bof1, int bdiv,
                               long cof0, long cof1, int cdiv, int zdiv)
{
    dim3 g(N / BN, M / BM, Z), blk(256);
    hipLaunchKernelGGL(gemm3, g, blk, 0, st, A, B, C, lda, ldb, ldc, K,
                       aof0, aof1, adiv, bof0, bof1, bdiv, cof0, cof1, cdiv, zdiv);
}

extern "C" void kernel_launch(void* const* d_in, const int* in_sizes, int n_in,
                              void* d_out, int out_size, void* d_ws, size_t ws_size,
                              hipStream_t stream)
{
    const float* hs   = (const float*)d_in[0];
    const float* cosb = (const float*)d_in[1];
    const float* sinb = (const float*)d_in[2];
    const float* Wq   = (const float*)d_in[4];
    const float* Wk   = (const float*)d_in[5];
    const float* Wv   = (const float*)d_in[6];
    const float* Wo   = (const float*)d_in[7];
    const float* qw   = (const float*)d_in[8];
    const float* kw   = (const float*)d_in[9];
    const float* lb   = (const float*)d_in[10];

    float* out  = (float*)d_out;                       // (B,S,D) = 4,194,304 floats
    float* attn = out + (long)Bb * Ss * Dd;            // (B,H,S,S) = 33,554,432 floats

    float* ws = (float*)d_ws;
    // qkv occupies ws[0 .. 8.39M); after the epilogue it is dead, so state2/stateF alias it.
    float* qkv    = ws;                                // 2048 x 4096
    float* state2 = ws;                                // (B,H,S,HD) 4,194,304
    float* stateF = ws + 4194304;                      // (B,S,H*HD) 4,194,304
    float* state  = ws + 8388608;                      // (B,H,S,HD) 4,194,304
    float* kbuf   = ws + 12582912;                     // (B,KV,S,HD) 2,097,152
    float* kT     = ws + 14680064;                     // (B,KV,HD,S) 2,097,152
    float* vT     = ws + 16777216;                     // (B,KV,HD,S) 2,097,152

    const long SH = (long)Ss * HDd;                    // 131072
    const long SS2 = (long)Ss * Ss;                    // 1,048,576

    // QKV projections: qkv[m, 0:2048]=q, [2048:3072]=k, [3072:4096]=v
    launch_gemm(stream, hs, Wq, qkv,        2048, 2048, 2048, 2048, 4096, 2048, 1, 0,0,1, 0,0,1, 0,0,1, 1);
    launch_gemm(stream, hs, Wk, qkv + 2048, 2048, 1024, 2048, 2048, 4096, 2048, 1, 0,0,1, 0,0,1, 0,0,1, 1);
    launch_gemm(stream, hs, Wv, qkv + 3072, 2048, 1024, 2048, 2048, 4096, 2048, 1, 0,0,1, 0,0,1, 0,0,1, 1);

    hipLaunchKernelGGL(qkv_epi, dim3(Bb * Ss), dim3(256), 0, stream,
                       qkv, cosb, sinb, qw, kw, state, kbuf, kT, vT);

    float* sA = state;
    float* sC = state2;
    for (int t = 0; t < 3; ++t) {
        // scores[z, q, j] = state[z, q, :] . k[z', j, :]   (z = b*H + h, z' uses kv = h/2)
        launch_gemm(stream, sA, kbuf, attn, 1024, 1024, 128, 128, 1024, 128, 32,
                    (long)Hh * SH, SH, 1,
                    (long)KVv * SH, SH, 2,
                    (long)Hh * SS2, SS2, 1, Hh);
        hipLaunchKernelGGL(softmax_causal, dim3(Ss, Bb * Hh), dim3(256), 0, stream, attn, lb);
        if (t < 2) {
            // state_new[z, q, d] = attn[z, q, :] . kT[z', d, :]
            launch_gemm(stream, attn, kT, sC, 1024, 128, 1024, 1024, 128, 1024, 32,
                        (long)Hh * SS2, SS2, 1,
                        (long)KVv * SH, SH, 2,
                        (long)Hh * SH, SH, 1, Hh);
            float* tmp = sA; sA = sC; sC = tmp;
        } else {
            // final: write directly in (B, S, H*HD) layout for the out-projection
            launch_gemm(stream, attn, vT, stateF, 1024, 128, 1024, 1024, 2048, 1024, 32,
                        (long)Hh * SS2, SS2, 1,
                        (long)KVv * SH, SH, 2,
                        (long)Ss * 2048, 128, 1, Hh);
        }
    }

    // out = stateF . Wo^T
    launch_gemm(stream, stateF, Wo, out, 2048, 2048, 2048, 2048, 2048, 2048, 1, 0,0,1, 0,0,1, 0,0,1, 1);
}

// Round 2
// 642.862 us; speedup vs baseline: 1.4477x; 1.4477x over previous
//
#include <hip/hip_runtime.h>
#include <hip/hip_bf16.h>

#define DEVI __device__ __forceinline__

typedef __attribute__((ext_vector_type(8))) short short8;
typedef __attribute__((ext_vector_type(4))) float f32x4;
typedef unsigned short u16;
typedef __attribute__((ext_vector_type(4))) u16 us4;
typedef __attribute__((ext_vector_type(8))) u16 us8;

DEVI u16 bfbits(float x) {
    union { __hip_bfloat16 b; u16 u; } cv;
    cv.b = __float2bfloat16(x);
    return cv.u;
}
DEVI float bff(u16 u) {
    union { u16 u; __hip_bfloat16 b; } cv;
    cv.u = u;
    return __bfloat162float(cv.b);
}

DEVI void gload16(const void* g, void* l) {
    __builtin_amdgcn_global_load_lds(
        (const __attribute__((address_space(1))) unsigned int*)g,
        (__attribute__((address_space(3))) unsigned int*)l, 16, 0, 0);
}

// Write a split (hi/lo) bf16 value into a swizzled block.
// Block layout: [128 rows][32 k] -> elem = r*64 + (k/8)*16 + lo*8 + (k%8), elem ^= (r&7)<<3
DEVI void wsplit(u16* buf, long bb, int r, int kc, float v) {
    const int sw = (r & 7) << 3;
    const int off = r * 64 + ((kc >> 3) << 4) + (kc & 7);
    u16 h = bfbits(v);
    buf[bb + (off ^ sw)] = h;
    buf[bb + ((off + 8) ^ sw)] = bfbits(v - bff(h));
}

// Stage 4 consecutive fp32 (row r, cols c0..c0+3 of a 32-wide k-tile) into swizzled split LDS.
DEVI void stage4(u16* L, int r, int c0, float4 v) {
    const int sw = (r & 7) << 3;
    const int kb = c0 >> 3, c4 = c0 & 7;
    float f[4] = {v.x, v.y, v.z, v.w};
    us4 h, l;
#pragma unroll
    for (int j = 0; j < 4; ++j) {
        u16 hh = bfbits(f[j]);
        h[j] = hh;
        l[j] = bfbits(f[j] - bff(hh));
    }
    *(us4*)(L + ((r * 64 + kb * 16 + c4) ^ sw)) = h;
    *(us4*)(L + ((r * 64 + kb * 16 + c4 + 8) ^ sw)) = l;
}

// Generic 128x128-tile GEMM, C = A * B^T, split-bf16 (3 MFMA) fp32 accumulate.
// AM: 1 = A presplit blocked (global_load_lds), 0 = A fp32 row-major (VALU split staging, aMT=lda)
// BMm: same for B
// CM: 0 = fp32 row-major out (cP0=ldc), 1 = split-blocked out (cP0=MtileStride, cP1=KtileStride)
// CAUSAL: 0 none, 1 = skip blocks with n0 > m0 (scores), 2 = limit k-tiles to m0/32+4 (PV)
template<int AM, int BMm, int CM, int CAUSAL>
__global__ __launch_bounds__(256) void gemmk(
    const void* __restrict__ Ap, const void* __restrict__ Bp, void* __restrict__ Cp,
    int nKt, int zdiv,
    long aZ0, long aZ1, int aDiv, long aMT,
    long bZ0, long bZ1, int bDiv, long bMT,
    long cZ0, long cZ1, int cDiv, long cP0, long cP1)
{
    const int z = blockIdx.z;
    const int zo = z / zdiv, zi = z - zo * zdiv;
    const int m0 = blockIdx.y * 128, n0 = blockIdx.x * 128;
    if (CAUSAL == 1 && n0 > m0) return;
    int kend = nKt;
    if (CAUSAL == 2) { int ke = (m0 >> 5) + 4; kend = ke < nKt ? ke : nKt; }

    __shared__ u16 LA[8192], LB[8192];
    const int tid = threadIdx.x, w = tid >> 6, lane = tid & 63;
    const int wr = (w >> 1) * 64, wc = (w & 1) * 64, fr = lane & 15, fkb = lane >> 4;

    const u16* Ab = nullptr; const float* Af = nullptr;
    if (AM == 1) Ab = (const u16*)Ap + zo * aZ0 + (long)(zi / aDiv) * aZ1 + (long)(m0 >> 7) * aMT;
    else         Af = (const float*)Ap + zo * aZ0 + (long)(zi / aDiv) * aZ1 + (long)m0 * aMT;
    const u16* Bb = nullptr; const float* Bf = nullptr;
    if (BMm == 1) Bb = (const u16*)Bp + zo * bZ0 + (long)(zi / bDiv) * bZ1 + (long)(n0 >> 7) * bMT;
    else          Bf = (const float*)Bp + zo * bZ0 + (long)(zi / bDiv) * bZ1 + (long)n0 * bMT;

    f32x4 acc[4][4] = {};

    for (int kt = 0; kt < kend; ++kt) {
        if (AM == 1) {
            const char* s = (const char*)(Ab + (long)kt * 8192);
#pragma unroll
            for (int i = 0; i < 4; ++i)
                gload16(s + i * 4096 + w * 1024 + lane * 16, (char*)LA + i * 4096 + w * 1024);
        } else {
#pragma unroll
            for (int i = 0; i < 4; ++i) {
                int idx = i * 256 + tid, r = idx >> 3, c0 = (idx & 7) << 2;
                float4 v = *reinterpret_cast<const float4*>(Af + (long)r * aMT + kt * 32 + c0);
                stage4(LA, r, c0, v);
            }
        }
        if (BMm == 1) {
            const char* s = (const char*)(Bb + (long)kt * 8192);
#pragma unroll
            for (int i = 0; i < 4; ++i)
                gload16(s + i * 4096 + w * 1024 + lane * 16, (char*)LB + i * 4096 + w * 1024);
        } else {
#pragma unroll
            for (int i = 0; i < 4; ++i) {
                int idx = i * 256 + tid, r = idx >> 3, c0 = (idx & 7) << 2;
                float4 v = *reinterpret_cast<const float4*>(Bf + (long)r * bMT + kt * 32 + c0);
                stage4(LB, r, c0, v);
            }
        }
        __syncthreads();

        short8 ah[4], al[4], bh[4], bl[4];
#pragma unroll
        for (int m = 0; m < 4; ++m) {
            int r = wr + m * 16 + fr, sw = (r & 7) << 3, base = r * 64 + fkb * 16;
            ah[m] = *(const short8*)(LA + (base ^ sw));
            al[m] = *(const short8*)(LA + ((base + 8) ^ sw));
        }
#pragma unroll
        for (int n = 0; n < 4; ++n) {
            int r = wc + n * 16 + fr, sw = (r & 7) << 3, base = r * 64 + fkb * 16;
            bh[n] = *(const short8*)(LB + (base ^ sw));
            bl[n] = *(const short8*)(LB + ((base + 8) ^ sw));
        }
#pragma unroll
        for (int m = 0; m < 4; ++m)
#pragma unroll
            for (int n = 0; n < 4; ++n) {
                acc[m][n] = __builtin_amdgcn_mfma_f32_16x16x32_bf16(ah[m], bh[n], acc[m][n], 0, 0, 0);
                acc[m][n] = __builtin_amdgcn_mfma_f32_16x16x32_bf16(ah[m], bl[n], acc[m][n], 0, 0, 0);
                acc[m][n] = __builtin_amdgcn_mfma_f32_16x16x32_bf16(al[m], bh[n], acc[m][n], 0, 0, 0);
            }
        __syncthreads();
    }

    if (CM == 0) {
        float* C = (float*)Cp + zo * cZ0 + (long)(zi / cDiv) * cZ1;
        const long ldc = cP0;
#pragma unroll
        for (int m = 0; m < 4; ++m)
#pragma unroll
            for (int j = 0; j < 4; ++j) {
                long row = m0 + wr + m * 16 + (lane >> 4) * 4 + j;
#pragma unroll
                for (int n = 0; n < 4; ++n)
                    C[row * ldc + n0 + wc + n * 16 + fr] = acc[m][n][j];
            }
    } else {
        u16* C = (u16*)Cp + zo * cZ0 + (long)(zi / cDiv) * cZ1 + (long)(m0 >> 7) * cP0;
#pragma unroll
        for (int n = 0; n < 4; ++n) {
            int colg = n0 + wc + n * 16 + fr;
            long kb_ = (long)(colg >> 5) * cP1;
            int off0 = ((colg >> 3) & 3) * 16 + (colg & 7);
#pragma unroll
            for (int m = 0; m < 4; ++m)
#pragma unroll
                for (int j = 0; j < 4; ++j) {
                    int r = wr + m * 16 + (lane >> 4) * 4 + j;
                    int sw = (r & 7) << 3;
                    float v = acc[m][n][j];
                    u16 h = bfbits(v);
                    C[kb_ + ((r * 64 + off0) ^ sw)] = h;
                    C[kb_ + ((r * 64 + off0 + 8) ^ sw)] = bfbits(v - bff(h));
                }
        }
    }
}

// fp32 [R][2048] row-major -> split-blocked [Rt][64][8192]. One row per block.
__global__ __launch_bounds__(256) void splitk(const float* __restrict__ in, u16* __restrict__ out) {
    const long t = (long)blockIdx.x * 256 + threadIdx.x;
    const int row = (int)(t >> 8), kg = (int)(t & 255);
    const int k0 = kg << 3;
    const float* src = in + (long)row * 2048 + k0;
    float4 a = *(const float4*)src, b = *(const float4*)(src + 4);
    float f[8] = {a.x, a.y, a.z, a.w, b.x, b.y, b.z, b.w};
    us8 h, l;
#pragma unroll
    for (int j = 0; j < 8; ++j) {
        u16 hh = bfbits(f[j]);
        h[j] = hh;
        l[j] = bfbits(f[j] - bff(hh));
    }
    const int Kt = k0 >> 5, kb = kg & 3, r = row & 127, Rt = row >> 7, sw = (r & 7) << 3;
    u16* o = out + ((long)Rt * 64 + Kt) * 8192;
    *(us8*)(o + ((r * 64 + kb * 16) ^ sw)) = h;
    *(us8*)(o + ((r * 64 + kb * 16 + 8) ^ sw)) = l;
}

// Wq (2048 rows) | Wk (1024) | Wv (1024) -> one blocked buffer, Rt 0..31
__global__ __launch_bounds__(256) void split3(const float* __restrict__ Wq, const float* __restrict__ Wk,
                                              const float* __restrict__ Wv, u16* __restrict__ out) {
    const long t = (long)blockIdx.x * 256 + threadIdx.x;
    const int row = (int)(t >> 8), kg = (int)(t & 255);
    const int k0 = kg << 3;
    const float* src;
    if (row < 2048)      src = Wq + (long)row * 2048 + k0;
    else if (row < 3072) src = Wk + (long)(row - 2048) * 2048 + k0;
    else                 src = Wv + (long)(row - 3072) * 2048 + k0;
    float4 a = *(const float4*)src, b = *(const float4*)(src + 4);
    float f[8] = {a.x, a.y, a.z, a.w, b.x, b.y, b.z, b.w};
    us8 h, l;
#pragma unroll
    for (int j = 0; j < 8; ++j) {
        u16 hh = bfbits(f[j]);
        h[j] = hh;
        l[j] = bfbits(f[j] - bff(hh));
    }
    const int Kt = k0 >> 5, kb = kg & 3, r = row & 127, Rt = row >> 7, sw = (r & 7) << 3;
    u16* o = out + ((long)Rt * 64 + Kt) * 8192;
    *(us8*)(o + ((r * 64 + kb * 16) ^ sw)) = h;
    *(us8*)(o + ((r * 64 + kb * 16 + 8) ^ sw)) = l;
}

// Per (b,s): RMSNorm + RoPE; q -> state_s (split blocked), k -> k_s + kT_s, v -> vT_s.
__global__ __launch_bounds__(256) void qkv_epi(
    const float* __restrict__ qkv, const float* __restrict__ cosb, const float* __restrict__ sinb,
    const float* __restrict__ qw, const float* __restrict__ kw,
    u16* __restrict__ state_s, u16* __restrict__ k_s,
    u16* __restrict__ kT_s, u16* __restrict__ vT_s)
{
    const int bs = blockIdx.x, b = bs >> 10, s = bs & 1023;
    const float* row = qkv + (long)bs * 4096;
    const int w = threadIdx.x >> 6, lane = threadIdx.x & 63;
    const float clo = cosb[(long)bs * 128 + lane], chi = cosb[(long)bs * 128 + 64 + lane];
    const float slo = sinb[(long)bs * 128 + lane], shi = sinb[(long)bs * 128 + 64 + lane];
    const int Mt = s >> 7, r = s & 127;
    const float qwl = qw[lane], qwh = qw[lane + 64], kwl = kw[lane], kwh = kw[lane + 64];

    for (int h = w; h < 16; h += 4) {
        float xlo = row[h * 128 + lane], xhi = row[h * 128 + 64 + lane];
        float ss = xlo * xlo + xhi * xhi;
#pragma unroll
        for (int o = 32; o; o >>= 1) ss += __shfl_xor(ss, o);
        float rr = 1.0f / sqrtf(ss * (1.0f / 128.0f) + 1e-6f);
        float ylo = xlo * rr * qwl, yhi = xhi * rr * qwh;
        float olo = ylo * clo - yhi * slo;
        float ohi = yhi * chi + ylo * shi;
        long zb = (long)(b * 16 + h) * 262144 + (long)Mt * 32768;
        wsplit(state_s, zb + (long)(lane >> 5) * 8192, r, lane & 31, olo);
        wsplit(state_s, zb + (long)(2 + (lane >> 5)) * 8192, r, lane & 31, ohi);
    }
    for (int kv = w; kv < 8; kv += 4) {
        float xlo = row[2048 + kv * 128 + lane], xhi = row[2048 + kv * 128 + 64 + lane];
        float ss = xlo * xlo + xhi * xhi;
#pragma unroll
        for (int o = 32; o; o >>= 1) ss += __shfl_xor(ss, o);
        float rr = 1.0f / sqrtf(ss * (1.0f / 128.0f) + 1e-6f);
        float ylo = xlo * rr * kwl, yhi = xhi * rr * kwh;
        float olo = ylo * clo - yhi * slo;
        float ohi = yhi * chi + ylo * shi;
        long zb = (long)(b * 8 + kv) * 262144 + (long)Mt * 32768;
        wsplit(k_s, zb + (long)(lane >> 5) * 8192, r, lane & 31, olo);
        wsplit(k_s, zb + (long)(2 + (lane >> 5)) * 8192, r, lane & 31, ohi);
        long tb = (long)(b * 8 + kv) * 262144 + (long)(s >> 5) * 8192;
        wsplit(kT_s, tb, lane, s & 31, olo);
        wsplit(kT_s, tb, lane + 64, s & 31, ohi);
    }
    for (int kv = w; kv < 8; kv += 4) {
        float xlo = row[3072 + kv * 128 + lane], xhi = row[3072 + kv * 128 + 64 + lane];
        long tb = (long)(b * 8 + kv) * 262144 + (long)(s >> 5) * 8192;
        wsplit(vT_s, tb, lane, s & 31, xlo);
        wsplit(vT_s, tb, lane + 64, s & 31, xhi);
    }
}

// Causal softmax over row `row` of (32,1024,1024). Scale by sb, mask col>row.
// FINAL=1: write full row fp32 (zeros beyond causal width). FINAL=0: write only [0,W).
template<int FINAL>
__global__ __launch_bounds__(256) void softmaxk(float* __restrict__ sc, const float* __restrict__ lb) {
    const int row = blockIdx.x;
    const long z = blockIdx.y;
    float* rp = sc + (z * 1024 + row) * 1024;
    const int W = ((row >> 7) + 1) << 7;
    const int tid = threadIdx.x, w = tid >> 6, lane = tid & 63;
    const float sb = 0.08838834764831845f * expf(lb[0]);
    const int c0 = tid * 4;
    const bool act = c0 < W;
    float x0 = -3e38f, x1 = -3e38f, x2 = -3e38f, x3 = -3e38f;
    if (act) {
        float4 v = *reinterpret_cast<const float4*>(rp + c0);
        x0 = (c0 + 0 <= row) ? v.x * sb : -3e38f;
        x1 = (c0 + 1 <= row) ? v.y * sb : -3e38f;
        x2 = (c0 + 2 <= row) ? v.z * sb : -3e38f;
        x3 = (c0 + 3 <= row) ? v.w * sb : -3e38f;
    }
    __shared__ float red[8];
    float mx = fmaxf(fmaxf(x0, x1), fmaxf(x2, x3));
#pragma unroll
    for (int o = 32; o; o >>= 1) mx = fmaxf(mx, __shfl_xor(mx, o));
    if (!lane) red[w] = mx;
    __syncthreads();
    mx = fmaxf(fmaxf(red[0], red[1]), fmaxf(red[2], red[3]));

    float e0 = expf(x0 - mx), e1 = expf(x1 - mx), e2 = expf(x2 - mx), e3 = expf(x3 - mx);
    float sm = e0 + e1 + e2 + e3;
#pragma unroll
    for (int o = 32; o; o >>= 1) sm += __shfl_xor(sm, o);
    if (!lane) red[4 + w] = sm;
    __syncthreads();
    sm = red[4] + red[5] + red[6] + red[7];
    float inv = 1.0f / sm;

    if (FINAL || act) {
        float4 o4;
        o4.x = e0 * inv; o4.y = e1 * inv; o4.z = e2 * inv; o4.w = e3 * inv;
        *reinterpret_cast<float4*>(rp + c0) = o4;
    }
}

extern "C" void kernel_launch(void* const* d_in, const int* in_sizes, int n_in,
                              void* d_out, int out_size, void* d_ws, size_t ws_size,
                              hipStream_t stream)
{
    const float* hs   = (const float*)d_in[0];
    const float* cosb = (const float*)d_in[1];
    const float* sinb = (const float*)d_in[2];
    const float* Wq   = (const float*)d_in[4];
    const float* Wk   = (const float*)d_in[5];
    const float* Wv   = (const float*)d_in[6];
    const float* Wo   = (const float*)d_in[7];
    const float* qw   = (const float*)d_in[8];
    const float* kw   = (const float*)d_in[9];
    const float* lb   = (const float*)d_in[10];

    float* out  = (float*)d_out;                 // (B,S,D)
    float* attn = out + 4194304;                 // (B,H,S,S)

    char* ws = (char*)d_ws;
    const bool full = ws_size >= 35651584ull * 4ull;

    u16 *Wqkv_s = nullptr, *Wo_s = nullptr, *hs_s = nullptr;
    u16 *state_s, *state2_s, *stateF_s, *k_s, *kT_s, *vT_s;
    float* qkv;
    if (full) {
        Wqkv_s   = (u16*)(ws);
        Wo_s     = (u16*)(ws + 8388608L * 4);
        hs_s     = (u16*)(ws + 12582912L * 4);
        qkv      = (float*)(ws + 16777216L * 4);
        state2_s = (u16*)qkv;                       // alias: qkv dead after epi
        stateF_s = (u16*)(ws + 20971520L * 4);      // alias: upper half of qkv region
        state_s  = (u16*)(ws + 25165824L * 4);
        k_s      = (u16*)(ws + 29360128L * 4);
        kT_s     = (u16*)(ws + 31457280L * 4);
        vT_s     = (u16*)(ws + 33554432L * 4);
    } else {
        qkv      = (float*)ws;
        state2_s = (u16*)ws;
        stateF_s = (u16*)(ws + 4194304L * 4);
        state_s  = (u16*)(ws + 8388608L * 4);
        k_s      = (u16*)(ws + 12582912L * 4);
        kT_s     = (u16*)(ws + 14680064L * 4);
        vT_s     = (u16*)(ws + 16777216L * 4);
    }

    if (full) {
        splitk<<<2048, 256, 0, stream>>>(hs, hs_s);
        split3<<<4096, 256, 0, stream>>>(Wq, Wk, Wv, Wqkv_s);
        splitk<<<2048, 256, 0, stream>>>(Wo, Wo_s);
        gemmk<1,1,0,0><<<dim3(32,16,1), 256, 0, stream>>>(hs_s, Wqkv_s, qkv, 64, 1,
            0L,0L,1, 524288L,  0L,0L,1, 524288L,  0L,0L,1, 4096L, 0L);
    } else {
        gemmk<0,0,0,0><<<dim3(16,16,1), 256, 0, stream>>>(hs, Wq, qkv, 64, 1,
            0L,0L,1, 2048L,  0L,0L,1, 2048L,  0L,0L,1, 4096L, 0L);
        gemmk<0,0,0,0><<<dim3(8,16,1), 256, 0, stream>>>(hs, Wk, qkv + 2048, 64, 1,
            0L,0L,1, 2048L,  0L,0L,1, 2048L,  0L,0L,1, 4096L, 0L);
        gemmk<0,0,0,0><<<dim3(8,16,1), 256, 0, stream>>>(hs, Wv, qkv + 3072, 64, 1,
            0L,0L,1, 2048L,  0L,0L,1, 2048L,  0L,0L,1, 4096L, 0L);
    }

    qkv_epi<<<2048, 256, 0, stream>>>(qkv, cosb, sinb, qw, kw, state_s, k_s, kT_s, vT_s);

    for (int t = 0; t < 3; ++t) {
        const u16* sA = (t == 1) ? state2_s : state_s;
        // scores = state . k^T  (raw, fp32 -> attn region)
        gemmk<1,1,0,1><<<dim3(8,8,32), 256, 0, stream>>>(sA, k_s, attn, 4, 16,
            4194304L, 262144L, 1, 32768L,
            2097152L, 262144L, 2, 32768L,
            16777216L, 1048576L, 1, 1024L, 0L);
        if (t == 2) softmaxk<1><<<dim3(1024,32), 256, 0, stream>>>(attn, lb);
        else        softmaxk<0><<<dim3(1024,32), 256, 0, stream>>>(attn, lb);
        if (t < 2) {
            u16* sC = (t == 0) ? state2_s : state_s;
            gemmk<0,1,1,2><<<dim3(1,8,32), 256, 0, stream>>>(attn, kT_s, sC, 32, 16,
                16777216L, 1048576L, 1, 1024L,
                2097152L, 262144L, 2, 262144L,
                4194304L, 262144L, 1, 32768L, 8192L);
        } else {
            gemmk<0,1,1,2><<<dim3(1,8,32), 256, 0, stream>>>(attn, vT_s, stateF_s, 32, 16,
                16777216L, 1048576L, 1, 1024L,
                2097152L, 262144L, 2, 262144L,
                4194304L, 32768L, 1, 524288L, 8192L);
        }
    }

    // out = stateF . Wo^T
    if (full) {
        gemmk<1,1,0,0><<<dim3(16,16,1), 256, 0, stream>>>(stateF_s, Wo_s, out, 64, 1,
            0L,0L,1, 524288L,  0L,0L,1, 524288L,  0L,0L,1, 2048L, 0L);
    } else {
        gemmk<1,0,0,0><<<dim3(16,16,1), 256, 0, stream>>>(stateF_s, Wo, out, 64, 1,
            0L,0L,1, 524288L,  0L,0L,1, 2048L,  0L,0L,1, 2048L, 0L);
    }
}

// Round 3
// 529.765 us; speedup vs baseline: 1.7568x; 1.2135x over previous
//
#include <hip/hip_runtime.h>
#include <hip/hip_bf16.h>

#define DEVI __device__ __forceinline__

typedef __attribute__((ext_vector_type(8))) short short8;
typedef __attribute__((ext_vector_type(4))) float f32x4;
typedef unsigned short u16;
typedef __attribute__((ext_vector_type(4))) u16 us4;
typedef __attribute__((ext_vector_type(8))) u16 us8;

DEVI u16 bfbits(float x) {
    union { __hip_bfloat16 b; u16 u; } cv;
    cv.b = __float2bfloat16(x);
    return cv.u;
}
DEVI float bff(u16 u) {
    union { u16 u; __hip_bfloat16 b; } cv;
    cv.u = u;
    return __bfloat162float(cv.b);
}

DEVI void gload16(const void* g, void* l) {
    __builtin_amdgcn_global_load_lds(
        (const __attribute__((address_space(1))) unsigned int*)g,
        (__attribute__((address_space(3))) unsigned int*)l, 16, 0, 0);
}

// ---- layouts ----
// SPLIT block: [128 rows][32 k] as u16[8192]: u16 idx = r*64 + (k/8)*16 + hi?0:8 + k%8, idx ^= (r&7)<<3
// SINGLE block: [128 rows][64 k] as u16[8192]: u16 idx = (r*64 + k) ^ ((r&7)<<3)

DEVI void wsplit(u16* buf, long bb, int r, int kc, float v) {
    const int sw = (r & 7) << 3;
    const int off = r * 64 + ((kc >> 3) << 4) + (kc & 7);
    u16 h = bfbits(v);
    buf[bb + (off ^ sw)] = h;
    buf[bb + ((off + 8) ^ sw)] = bfbits(v - bff(h));
}

DEVI void stage4(u16* L, int r, int c0, float4 v) {
    const int sw = (r & 7) << 3;
    const int kb = c0 >> 3, c4 = c0 & 7;
    float f[4] = {v.x, v.y, v.z, v.w};
    us4 h, l;
#pragma unroll
    for (int j = 0; j < 4; ++j) {
        u16 hh = bfbits(f[j]);
        h[j] = hh;
        l[j] = bfbits(f[j] - bff(hh));
    }
    *(us4*)(L + ((r * 64 + kb * 16 + c4) ^ sw)) = h;
    *(us4*)(L + ((r * 64 + kb * 16 + c4 + 8) ^ sw)) = l;
}

// Generic 128x128-tile GEMM, C = A * B^T, split-bf16 (3 MFMA) fp32 accumulate.
template<int AM, int BMm, int CM, int CAUSAL>
__global__ __launch_bounds__(256) void gemmk(
    const void* __restrict__ Ap, const void* __restrict__ Bp, void* __restrict__ Cp,
    int nKt, int zdiv,
    long aZ0, long aZ1, int aDiv, long aMT,
    long bZ0, long bZ1, int bDiv, long bMT,
    long cZ0, long cZ1, int cDiv, long cP0, long cP1)
{
    const int z = blockIdx.z;
    const int zo = z / zdiv, zi = z - zo * zdiv;
    const int m0 = blockIdx.y * 128, n0 = blockIdx.x * 128;
    if (CAUSAL == 1 && n0 > m0) return;
    int kend = nKt;
    if (CAUSAL == 2) { int ke = (m0 >> 5) + 4; kend = ke < nKt ? ke : nKt; }

    __shared__ u16 LA[8192], LB[8192];
    const int tid = threadIdx.x, w = tid >> 6, lane = tid & 63;
    const int wr = (w >> 1) * 64, wc = (w & 1) * 64, fr = lane & 15, fkb = lane >> 4;

    const u16* Ab = nullptr; const float* Af = nullptr;
    if (AM == 1) Ab = (const u16*)Ap + zo * aZ0 + (long)(zi / aDiv) * aZ1 + (long)(m0 >> 7) * aMT;
    else         Af = (const float*)Ap + zo * aZ0 + (long)(zi / aDiv) * aZ1 + (long)m0 * aMT;
    const u16* Bb = nullptr; const float* Bf = nullptr;
    if (BMm == 1) Bb = (const u16*)Bp + zo * bZ0 + (long)(zi / bDiv) * bZ1 + (long)(n0 >> 7) * bMT;
    else          Bf = (const float*)Bp + zo * bZ0 + (long)(zi / bDiv) * bZ1 + (long)n0 * bMT;

    f32x4 acc[4][4] = {};

    for (int kt = 0; kt < kend; ++kt) {
        if (AM == 1) {
            const char* s = (const char*)(Ab + (long)kt * 8192);
#pragma unroll
            for (int i = 0; i < 4; ++i)
                gload16(s + i * 4096 + w * 1024 + lane * 16, (char*)LA + i * 4096 + w * 1024);
        } else {
#pragma unroll
            for (int i = 0; i < 4; ++i) {
                int idx = i * 256 + tid, r = idx >> 3, c0 = (idx & 7) << 2;
                float4 v = *reinterpret_cast<const float4*>(Af + (long)r * aMT + kt * 32 + c0);
                stage4(LA, r, c0, v);
            }
        }
        if (BMm == 1) {
            const char* s = (const char*)(Bb + (long)kt * 8192);
#pragma unroll
            for (int i = 0; i < 4; ++i)
                gload16(s + i * 4096 + w * 1024 + lane * 16, (char*)LB + i * 4096 + w * 1024);
        } else {
#pragma unroll
            for (int i = 0; i < 4; ++i) {
                int idx = i * 256 + tid, r = idx >> 3, c0 = (idx & 7) << 2;
                float4 v = *reinterpret_cast<const float4*>(Bf + (long)r * bMT + kt * 32 + c0);
                stage4(LB, r, c0, v);
            }
        }
        __syncthreads();

        short8 ah[4], al[4], bh[4], bl[4];
#pragma unroll
        for (int m = 0; m < 4; ++m) {
            int r = wr + m * 16 + fr, sw = (r & 7) << 3, base = r * 64 + fkb * 16;
            ah[m] = *(const short8*)(LA + (base ^ sw));
            al[m] = *(const short8*)(LA + ((base + 8) ^ sw));
        }
#pragma unroll
        for (int n = 0; n < 4; ++n) {
            int r = wc + n * 16 + fr, sw = (r & 7) << 3, base = r * 64 + fkb * 16;
            bh[n] = *(const short8*)(LB + (base ^ sw));
            bl[n] = *(const short8*)(LB + ((base + 8) ^ sw));
        }
#pragma unroll
        for (int m = 0; m < 4; ++m)
#pragma unroll
            for (int n = 0; n < 4; ++n) {
                acc[m][n] = __builtin_amdgcn_mfma_f32_16x16x32_bf16(ah[m], bh[n], acc[m][n], 0, 0, 0);
                acc[m][n] = __builtin_amdgcn_mfma_f32_16x16x32_bf16(ah[m], bl[n], acc[m][n], 0, 0, 0);
                acc[m][n] = __builtin_amdgcn_mfma_f32_16x16x32_bf16(al[m], bh[n], acc[m][n], 0, 0, 0);
            }
        __syncthreads();
    }

    if (CM == 0) {
        float* C = (float*)Cp + zo * cZ0 + (long)(zi / cDiv) * cZ1;
        const long ldc = cP0;
#pragma unroll
        for (int m = 0; m < 4; ++m)
#pragma unroll
            for (int j = 0; j < 4; ++j) {
                long row = m0 + wr + m * 16 + (lane >> 4) * 4 + j;
#pragma unroll
                for (int n = 0; n < 4; ++n)
                    C[row * ldc + n0 + wc + n * 16 + fr] = acc[m][n][j];
            }
    } else {
        u16* C = (u16*)Cp + zo * cZ0 + (long)(zi / cDiv) * cZ1 + (long)(m0 >> 7) * cP0;
#pragma unroll
        for (int n = 0; n < 4; ++n) {
            int colg = n0 + wc + n * 16 + fr;
            long kb_ = (long)(colg >> 5) * cP1;
            int off0 = ((colg >> 3) & 3) * 16 + (colg & 7);
#pragma unroll
            for (int m = 0; m < 4; ++m)
#pragma unroll
                for (int j = 0; j < 4; ++j) {
                    int r = wr + m * 16 + (lane >> 4) * 4 + j;
                    int sw = (r & 7) << 3;
                    float v = acc[m][n][j];
                    u16 h = bfbits(v);
                    C[kb_ + ((r * 64 + off0) ^ sw)] = h;
                    C[kb_ + ((r * 64 + off0 + 8) ^ sw)] = bfbits(v - bff(h));
                }
        }
    }
}

// fp32 [R][2048] row-major -> split-blocked [Rt][64][8192]
__global__ __launch_bounds__(256) void splitk(const float* __restrict__ in, u16* __restrict__ out) {
    const long t = (long)blockIdx.x * 256 + threadIdx.x;
    const int row = (int)(t >> 8), kg = (int)(t & 255);
    const int k0 = kg << 3;
    const float* src = in + (long)row * 2048 + k0;
    float4 a = *(const float4*)src, b = *(const float4*)(src + 4);
    float f[8] = {a.x, a.y, a.z, a.w, b.x, b.y, b.z, b.w};
    us8 h, l;
#pragma unroll
    for (int j = 0; j < 8; ++j) {
        u16 hh = bfbits(f[j]);
        h[j] = hh;
        l[j] = bfbits(f[j] - bff(hh));
    }
    const int Kt = k0 >> 5, kb = kg & 3, r = row & 127, Rt = row >> 7, sw = (r & 7) << 3;
    u16* o = out + ((long)Rt * 64 + Kt) * 8192;
    *(us8*)(o + ((r * 64 + kb * 16) ^ sw)) = h;
    *(us8*)(o + ((r * 64 + kb * 16 + 8) ^ sw)) = l;
}

__global__ __launch_bounds__(256) void split3(const float* __restrict__ Wq, const float* __restrict__ Wk,
                                              const float* __restrict__ Wv, u16* __restrict__ out) {
    const long t = (long)blockIdx.x * 256 + threadIdx.x;
    const int row = (int)(t >> 8), kg = (int)(t & 255);
    const int k0 = kg << 3;
    const float* src;
    if (row < 2048)      src = Wq + (long)row * 2048 + k0;
    else if (row < 3072) src = Wk + (long)(row - 2048) * 2048 + k0;
    else                 src = Wv + (long)(row - 3072) * 2048 + k0;
    float4 a = *(const float4*)src, b = *(const float4*)(src + 4);
    float f[8] = {a.x, a.y, a.z, a.w, b.x, b.y, b.z, b.w};
    us8 h, l;
#pragma unroll
    for (int j = 0; j < 8; ++j) {
        u16 hh = bfbits(f[j]);
        h[j] = hh;
        l[j] = bfbits(f[j] - bff(hh));
    }
    const int Kt = k0 >> 5, kb = kg & 3, r = row & 127, Rt = row >> 7, sw = (r & 7) << 3;
    u16* o = out + ((long)Rt * 64 + Kt) * 8192;
    *(us8*)(o + ((r * 64 + kb * 16) ^ sw)) = h;
    *(us8*)(o + ((r * 64 + kb * 16 + 8) ^ sw)) = l;
}

// RMSNorm + RoPE epilogue. state/k split-blocked; kT/vT single-bf16 blocked.
__global__ __launch_bounds__(256) void qkv_epi(
    const float* __restrict__ qkv, const float* __restrict__ cosb, const float* __restrict__ sinb,
    const float* __restrict__ qw, const float* __restrict__ kw,
    u16* __restrict__ state_s, u16* __restrict__ k_s,
    u16* __restrict__ kT_s, u16* __restrict__ vT_s)
{
    const int bs = blockIdx.x, b = bs >> 10, s = bs & 1023;
    const float* row = qkv + (long)bs * 4096;
    const int w = threadIdx.x >> 6, lane = threadIdx.x & 63;
    const float clo = cosb[(long)bs * 128 + lane], chi = cosb[(long)bs * 128 + 64 + lane];
    const float slo = sinb[(long)bs * 128 + lane], shi = sinb[(long)bs * 128 + 64 + lane];
    const int Mt = s >> 7, r = s & 127;
    const float qwl = qw[lane], qwh = qw[lane + 64], kwl = kw[lane], kwh = kw[lane + 64];

    for (int h = w; h < 16; h += 4) {
        float xlo = row[h * 128 + lane], xhi = row[h * 128 + 64 + lane];
        float ss = xlo * xlo + xhi * xhi;
#pragma unroll
        for (int o = 32; o; o >>= 1) ss += __shfl_xor(ss, o);
        float rr = 1.0f / sqrtf(ss * (1.0f / 128.0f) + 1e-6f);
        float ylo = xlo * rr * qwl, yhi = xhi * rr * qwh;
        float olo = ylo * clo - yhi * slo;
        float ohi = yhi * chi + ylo * shi;
        long zb = (long)(b * 16 + h) * 262144 + (long)Mt * 32768;
        wsplit(state_s, zb + (long)(lane >> 5) * 8192, r, lane & 31, olo);
        wsplit(state_s, zb + (long)(2 + (lane >> 5)) * 8192, r, lane & 31, ohi);
    }
    for (int kv = w; kv < 8; kv += 4) {
        float xlo = row[2048 + kv * 128 + lane], xhi = row[2048 + kv * 128 + 64 + lane];
        float ss = xlo * xlo + xhi * xhi;
#pragma unroll
        for (int o = 32; o; o >>= 1) ss += __shfl_xor(ss, o);
        float rr = 1.0f / sqrtf(ss * (1.0f / 128.0f) + 1e-6f);
        float ylo = xlo * rr * kwl, yhi = xhi * rr * kwh;
        float olo = ylo * clo - yhi * slo;
        float ohi = yhi * chi + ylo * shi;
        long zb = (long)(b * 8 + kv) * 262144 + (long)Mt * 32768;
        wsplit(k_s, zb + (long)(lane >> 5) * 8192, r, lane & 31, olo);
        wsplit(k_s, zb + (long)(2 + (lane >> 5)) * 8192, r, lane & 31, ohi);
        long tb = (long)(b * 8 + kv) * 131072 + (long)(s >> 6) * 8192;
        const int c = s & 63, sw = (lane & 7) << 3;
        kT_s[tb + ((lane * 64 + c) ^ sw)] = bfbits(olo);
        kT_s[tb + (((lane + 64) * 64 + c) ^ sw)] = bfbits(ohi);
    }
    for (int kv = w; kv < 8; kv += 4) {
        float xlo = row[3072 + kv * 128 + lane], xhi = row[3072 + kv * 128 + 64 + lane];
        long tb = (long)(b * 8 + kv) * 131072 + (long)(s >> 6) * 8192;
        const int c = s & 63, sw = (lane & 7) << 3;
        vT_s[tb + ((lane * 64 + c) ^ sw)] = bfbits(xlo);
        vT_s[tb + (((lane + 64) * 64 + c) ^ sw)] = bfbits(xhi);
    }
}

// Fused Hopfield step (t<2): scores (split QK^T) + online softmax + PV (single bf16).
// grid (qt=8, z=32). Sin/Sout: [z][8 Mt][4 ksub][8192] split. Ks split; KTs single.
__global__ __launch_bounds__(256) void hopstep(
    const u16* __restrict__ Sin, const u16* __restrict__ Ks,
    const u16* __restrict__ KTs, const float* __restrict__ lb,
    u16* __restrict__ Sout)
{
    const int qt = blockIdx.x, z = blockIdx.y;
    const int b = z >> 4, h = z & 15;
    const int zp = b * 8 + (h >> 1);
    const float sb = 0.08838834764831845f * expf(lb[0]);

    __shared__ u16 LQ[4][8192];   // Q tile resident (split)
    __shared__ u16 LK[8192];      // K subtile (split) / kT sblock (single)
    __shared__ u16 LP[8192];      // P half-tile (single)

    const int tid = threadIdx.x, w = tid >> 6, lane = tid & 63;
    const int fr = lane & 15, fkb = lane >> 4;
    const int wr = w * 32;

    const char* Qg = (const char*)(Sin + (long)z * 262144 + (long)qt * 32768);
#pragma unroll
    for (int ks = 0; ks < 4; ++ks)
#pragma unroll
        for (int i = 0; i < 4; ++i)
            gload16(Qg + ks * 16384 + i * 4096 + w * 1024 + lane * 16,
                    (char*)LQ[ks] + i * 4096 + w * 1024);

    f32x4 po[2][8] = {};
    float mrun[2][4], lrun[2][4];
#pragma unroll
    for (int m = 0; m < 2; ++m)
#pragma unroll
        for (int j = 0; j < 4; ++j) { mrun[m][j] = -3e38f; lrun[m][j] = 0.f; }

    const char* Kz  = (const char*)(Ks + (long)zp * 262144);
    const char* KTz = (const char*)(KTs + (long)zp * 131072);

#pragma unroll 1
    for (int jt = 0; jt <= qt; ++jt) {
        f32x4 ps[2][8] = {};
#pragma unroll 1
        for (int ks = 0; ks < 4; ++ks) {
            __syncthreads();
#pragma unroll
            for (int i = 0; i < 4; ++i)
                gload16(Kz + (long)jt * 65536 + ks * 16384 + i * 4096 + w * 1024 + lane * 16,
                        (char*)LK + i * 4096 + w * 1024);
            __syncthreads();
            short8 ah[2], al[2];
#pragma unroll
            for (int m = 0; m < 2; ++m) {
                int r = wr + m * 16 + fr, sw = (r & 7) << 3, base = r * 64 + fkb * 16;
                ah[m] = *(const short8*)(LQ[ks] + (base ^ sw));
                al[m] = *(const short8*)(LQ[ks] + ((base + 8) ^ sw));
            }
#pragma unroll
            for (int n = 0; n < 8; ++n) {
                int r = n * 16 + fr, sw = (r & 7) << 3, base = r * 64 + fkb * 16;
                short8 bh = *(const short8*)(LK + (base ^ sw));
                short8 bl = *(const short8*)(LK + ((base + 8) ^ sw));
#pragma unroll
                for (int m = 0; m < 2; ++m) {
                    ps[m][n] = __builtin_amdgcn_mfma_f32_16x16x32_bf16(ah[m], bh, ps[m][n], 0, 0, 0);
                    ps[m][n] = __builtin_amdgcn_mfma_f32_16x16x32_bf16(ah[m], bl, ps[m][n], 0, 0, 0);
                    ps[m][n] = __builtin_amdgcn_mfma_f32_16x16x32_bf16(al[m], bh, ps[m][n], 0, 0, 0);
                }
            }
        }
        // scale + causal mask (diag tile only)
        const bool diag = (jt == qt);
#pragma unroll
        for (int m = 0; m < 2; ++m)
#pragma unroll
            for (int n = 0; n < 8; ++n)
#pragma unroll
                for (int j = 0; j < 4; ++j) {
                    float v = ps[m][n][j] * sb;
                    if (diag && (n * 16 + fr) > (wr + m * 16 + fkb * 4 + j)) v = -3e38f;
                    ps[m][n][j] = v;
                }
        // online softmax update (rows live in 16-lane groups: shfl over lane&15)
#pragma unroll
        for (int m = 0; m < 2; ++m)
#pragma unroll
            for (int j = 0; j < 4; ++j) {
                float mx = ps[m][0][j];
#pragma unroll
                for (int n = 1; n < 8; ++n) mx = fmaxf(mx, ps[m][n][j]);
                mx = fmaxf(mx, __shfl_xor(mx, 1));
                mx = fmaxf(mx, __shfl_xor(mx, 2));
                mx = fmaxf(mx, __shfl_xor(mx, 4));
                mx = fmaxf(mx, __shfl_xor(mx, 8));
                float nm = fmaxf(mrun[m][j], mx);
                float scl = expf(mrun[m][j] - nm);
                mrun[m][j] = nm;
                float rs = 0.f;
#pragma unroll
                for (int n = 0; n < 8; ++n) {
                    float p = expf(ps[m][n][j] - nm);
                    ps[m][n][j] = p;
                    rs += p;
                    po[m][n][j] *= scl;
                }
                rs += __shfl_xor(rs, 1);
                rs += __shfl_xor(rs, 2);
                rs += __shfl_xor(rs, 4);
                rs += __shfl_xor(rs, 8);
                lrun[m][j] = lrun[m][j] * scl + rs;
            }
        // PV in two 64-col halves: P -> LP (single bf16), kT sblock -> LK
#pragma unroll
        for (int jh = 0; jh < 2; ++jh) {
            __syncthreads();
#pragma unroll
            for (int m = 0; m < 2; ++m)
#pragma unroll
                for (int nn = 0; nn < 4; ++nn)
#pragma unroll
                    for (int j = 0; j < 4; ++j) {
                        int r = wr + m * 16 + fkb * 4 + j;
                        LP[(r * 64 + nn * 16 + fr) ^ ((r & 7) << 3)] = bfbits(ps[m][jh * 4 + nn][j]);
                    }
#pragma unroll
            for (int i = 0; i < 4; ++i)
                gload16(KTz + (long)(jt * 2 + jh) * 16384 + i * 4096 + w * 1024 + lane * 16,
                        (char*)LK + i * 4096 + w * 1024);
            __syncthreads();
#pragma unroll
            for (int s2 = 0; s2 < 2; ++s2) {
                short8 pa[2];
#pragma unroll
                for (int m = 0; m < 2; ++m) {
                    int r = wr + m * 16 + fr;
                    pa[m] = *(const short8*)(LP + ((r * 64 + s2 * 32 + fkb * 8) ^ ((r & 7) << 3)));
                }
#pragma unroll
                for (int n = 0; n < 8; ++n) {
                    int r = n * 16 + fr;
                    short8 vb = *(const short8*)(LK + ((r * 64 + s2 * 32 + fkb * 8) ^ ((r & 7) << 3)));
#pragma unroll
                    for (int m = 0; m < 2; ++m)
                        po[m][n] = __builtin_amdgcn_mfma_f32_16x16x32_bf16(pa[m], vb, po[m][n], 0, 0, 0);
                }
            }
        }
    }
    // epilogue: normalize, exact split, write state
    u16* outp = Sout + (long)z * 262144 + (long)qt * 32768;
#pragma unroll
    for (int m = 0; m < 2; ++m)
#pragma unroll
        for (int j = 0; j < 4; ++j) {
            float inv = 1.0f / lrun[m][j];
            int r = wr + m * 16 + fkb * 4 + j, sw = (r & 7) << 3;
#pragma unroll
            for (int n = 0; n < 8; ++n) {
                int colg = n * 16 + fr;
                long base = (long)(colg >> 5) * 8192;
                int off0 = ((colg >> 3) & 3) * 16 + (colg & 7);
                float v = po[m][n][j] * inv;
                u16 hh = bfbits(v);
                outp[base + ((r * 64 + off0) ^ sw)] = hh;
                outp[base + ((r * 64 + off0 + 8) ^ sw)] = bfbits(v - bff(hh));
            }
        }
}

// Final softmax: raw scores (attn) -> normalized fp32 full row (zeros past causal)
// + single-bf16 blocked P_s (packed causal: z*72 + qt*(qt+1) sblocks).
__global__ __launch_bounds__(256) void softmaxF(
    float* __restrict__ sc, const float* __restrict__ lb, u16* __restrict__ P_s)
{
    const int row = blockIdx.x;
    const long z = blockIdx.y;
    float* rp = sc + (z * 1024 + row) * 1024;
    const int W = ((row >> 7) + 1) << 7, qt = row >> 7;
    const int tid = threadIdx.x, w = tid >> 6, lane = tid & 63;
    const float sb = 0.08838834764831845f * expf(lb[0]);
    const int c0 = tid * 4;
    const bool act = c0 < W;
    float x0 = -3e38f, x1 = -3e38f, x2 = -3e38f, x3 = -3e38f;
    if (act) {
        float4 v = *reinterpret_cast<const float4*>(rp + c0);
        x0 = (c0 + 0 <= row) ? v.x * sb : -3e38f;
        x1 = (c0 + 1 <= row) ? v.y * sb : -3e38f;
        x2 = (c0 + 2 <= row) ? v.z * sb : -3e38f;
        x3 = (c0 + 3 <= row) ? v.w * sb : -3e38f;
    }
    __shared__ float red[8];
    float mx = fmaxf(fmaxf(x0, x1), fmaxf(x2, x3));
#pragma unroll
    for (int o = 32; o; o >>= 1) mx = fmaxf(mx, __shfl_xor(mx, o));
    if (!lane) red[w] = mx;
    __syncthreads();
    mx = fmaxf(fmaxf(red[0], red[1]), fmaxf(red[2], red[3]));

    float e0 = expf(x0 - mx), e1 = expf(x1 - mx), e2 = expf(x2 - mx), e3 = expf(x3 - mx);
    float sm = e0 + e1 + e2 + e3;
#pragma unroll
    for (int o = 32; o; o >>= 1) sm += __shfl_xor(sm, o);
    if (!lane) red[4 + w] = sm;
    __syncthreads();
    sm = red[4] + red[5] + red[6] + red[7];
    float inv = 1.0f / sm;

    float p0 = e0 * inv, p1 = e1 * inv, p2 = e2 * inv, p3 = e3 * inv;
    float4 o4; o4.x = p0; o4.y = p1; o4.z = p2; o4.w = p3;
    *reinterpret_cast<float4*>(rp + c0) = o4;
    if (act) {
        const int r = row & 127, sw = (r & 7) << 3;
        long idx = z * 589824 + (long)qt * (qt + 1) * 8192 + (long)(c0 >> 6) * 8192
                 + ((r * 64 + (c0 & 63)) ^ sw);
        us4 pw; pw[0] = bfbits(p0); pw[1] = bfbits(p1); pw[2] = bfbits(p2); pw[3] = bfbits(p3);
        *(us4*)(P_s + idx) = pw;
    }
}

// Final PV: stateF = P . V (single x single), split-blocked output for out-proj.
// grid (qt=8, z=32).
__global__ __launch_bounds__(256) void pvfin(
    const u16* __restrict__ P_s, const u16* __restrict__ vT_s, u16* __restrict__ stateF)
{
    const int qt = blockIdx.x, z = blockIdx.y;
    const int b = z >> 4, h = z & 15;
    const int zp = b * 8 + (h >> 1);
    __shared__ u16 LA[8192], LB[8192];
    const int tid = threadIdx.x, w = tid >> 6, lane = tid & 63;
    const int fr = lane & 15, fkb = lane >> 4;
    const int wr = w * 32;

    const char* Pa = (const char*)(P_s + (long)z * 589824 + (long)qt * (qt + 1) * 8192);
    const char* Vz = (const char*)(vT_s + (long)zp * 131072);
    const int nj = 2 * qt + 2;

    f32x4 po[2][8] = {};
#pragma unroll 1
    for (int jsb = 0; jsb < nj; ++jsb) {
        __syncthreads();
#pragma unroll
        for (int i = 0; i < 4; ++i) {
            gload16(Pa + (long)jsb * 16384 + i * 4096 + w * 1024 + lane * 16,
                    (char*)LA + i * 4096 + w * 1024);
            gload16(Vz + (long)jsb * 16384 + i * 4096 + w * 1024 + lane * 16,
                    (char*)LB + i * 4096 + w * 1024);
        }
        __syncthreads();
#pragma unroll
        for (int s2 = 0; s2 < 2; ++s2) {
            short8 pa[2];
#pragma unroll
            for (int m = 0; m < 2; ++m) {
                int r = wr + m * 16 + fr;
                pa[m] = *(const short8*)(LA + ((r * 64 + s2 * 32 + fkb * 8) ^ ((r & 7) << 3)));
            }
#pragma unroll
            for (int n = 0; n < 8; ++n) {
                int r = n * 16 + fr;
                short8 vb = *(const short8*)(LB + ((r * 64 + s2 * 32 + fkb * 8) ^ ((r & 7) << 3)));
#pragma unroll
                for (int m = 0; m < 2; ++m)
                    po[m][n] = __builtin_amdgcn_mfma_f32_16x16x32_bf16(pa[m], vb, po[m][n], 0, 0, 0);
            }
        }
    }
    // split write to stateF [16 Mt][64 Kt][8192]
#pragma unroll
    for (int m = 0; m < 2; ++m)
#pragma unroll
        for (int j = 0; j < 4; ++j) {
            int r = wr + m * 16 + fkb * 4 + j, sw = (r & 7) << 3;
#pragma unroll
            for (int n = 0; n < 8; ++n) {
                int colg = n * 16 + fr;
                long base = (long)(b * 8 + qt) * 524288 + (long)(h * 4 + (colg >> 5)) * 8192;
                int off0 = ((colg >> 3) & 3) * 16 + (colg & 7);
                float v = po[m][n][j];
                u16 hh = bfbits(v);
                stateF[base + ((r * 64 + off0) ^ sw)] = hh;
                stateF[base + ((r * 64 + off0 + 8) ^ sw)] = bfbits(v - bff(hh));
            }
        }
}

extern "C" void kernel_launch(void* const* d_in, const int* in_sizes, int n_in,
                              void* d_out, int out_size, void* d_ws, size_t ws_size,
                              hipStream_t stream)
{
    const float* hs   = (const float*)d_in[0];
    const float* cosb = (const float*)d_in[1];
    const float* sinb = (const float*)d_in[2];
    const float* Wq   = (const float*)d_in[4];
    const float* Wk   = (const float*)d_in[5];
    const float* Wv   = (const float*)d_in[6];
    const float* Wo   = (const float*)d_in[7];
    const float* qw   = (const float*)d_in[8];
    const float* kw   = (const float*)d_in[9];
    const float* lb   = (const float*)d_in[10];

    float* out  = (float*)d_out;
    float* attn = out + 4194304;

    char* ws = (char*)d_ws;
    const bool full = ws_size >= 134217728ull;

    u16 *Wqkv_s = nullptr, *Wo_s = nullptr, *hs_s = nullptr;
    u16 *state_s, *state2_s, *stateF_s, *k_s, *kT_s, *vT_s, *P_s;
    float* qkv;
    if (full) {
        Wqkv_s   = (u16*)(ws);                       // 33.5M, dead after QKV gemm
        hs_s     = (u16*)(ws + 33554432L);           // 16.8M, dead after QKV gemm
        P_s      = (u16*)(ws);                       // 37.75M, alias (used from t=2 softmax)
        Wo_s     = (u16*)(ws + 50331648L);
        qkv      = (float*)(ws + 67108864L);         // dead after epi
        state2_s = (u16*)(ws + 67108864L);
        stateF_s = (u16*)(ws + 83886080L);
        state_s  = (u16*)(ws + 100663296L);
        k_s      = (u16*)(ws + 117440512L);
        kT_s     = (u16*)(ws + 125829120L);
        vT_s     = (u16*)(ws + 130023424L);
    } else {
        qkv      = (float*)ws;                       // 33.5M, dead after epi
        state2_s = (u16*)ws;
        stateF_s = (u16*)(ws + 16777216L);
        state_s  = (u16*)(ws + 33554432L);
        k_s      = (u16*)(ws + 50331648L);
        kT_s     = (u16*)(ws + 58720256L);
        vT_s     = (u16*)(ws + 62914560L);
        P_s      = (u16*)(ws + 67108864L);
    }

    if (full) {
        splitk<<<2048, 256, 0, stream>>>(hs, hs_s);
        split3<<<4096, 256, 0, stream>>>(Wq, Wk, Wv, Wqkv_s);
        splitk<<<2048, 256, 0, stream>>>(Wo, Wo_s);
        gemmk<1,1,0,0><<<dim3(32,16,1), 256, 0, stream>>>(hs_s, Wqkv_s, qkv, 64, 1,
            0L,0L,1, 524288L,  0L,0L,1, 524288L,  0L,0L,1, 4096L, 0L);
    } else {
        splitk<<<2048, 256, 0, stream>>>(Wo, (u16*)P_s);  // temp: pre-split Wo into P_s region
        gemmk<0,0,0,0><<<dim3(16,16,1), 256, 0, stream>>>(hs, Wq, qkv, 64, 1,
            0L,0L,1, 2048L,  0L,0L,1, 2048L,  0L,0L,1, 4096L, 0L);
        gemmk<0,0,0,0><<<dim3(8,16,1), 256, 0, stream>>>(hs, Wk, qkv + 2048, 64, 1,
            0L,0L,1, 2048L,  0L,0L,1, 2048L,  0L,0L,1, 4096L, 0L);
        gemmk<0,0,0,0><<<dim3(8,16,1), 256, 0, stream>>>(hs, Wv, qkv + 3072, 64, 1,
            0L,0L,1, 2048L,  0L,0L,1, 2048L,  0L,0L,1, 4096L, 0L);
    }

    qkv_epi<<<2048, 256, 0, stream>>>(qkv, cosb, sinb, qw, kw, state_s, k_s, kT_s, vT_s);

    // t = 0, 1 fused
    hopstep<<<dim3(8,32), 256, 0, stream>>>(state_s, k_s, kT_s, lb, state2_s);
    hopstep<<<dim3(8,32), 256, 0, stream>>>(state2_s, k_s, kT_s, lb, state_s);

    // t = 2: raw scores -> softmax (fp32 out + bf16 P) -> PV
    gemmk<1,1,0,1><<<dim3(8,8,32), 256, 0, stream>>>(state_s, k_s, attn, 4, 16,
        4194304L, 262144L, 1, 32768L,
        2097152L, 262144L, 2, 32768L,
        16777216L, 1048576L, 1, 1024L, 0L);
    softmaxF<<<dim3(1024,32), 256, 0, stream>>>(attn, lb, P_s);
    pvfin<<<dim3(8,32), 256, 0, stream>>>(P_s, vT_s, stateF_s);

    // out = stateF . Wo^T
    if (full) {
        gemmk<1,1,0,0><<<dim3(16,16,1), 256, 0, stream>>>(stateF_s, Wo_s, out, 64, 1,
            0L,0L,1, 524288L,  0L,0L,1, 524288L,  0L,0L,1, 2048L, 0L);
    } else {
        // Wo pre-split was placed in P_s region, but P_s is needed from t=2; re-split now into qkv region (dead)
        gemmk<1,1,0,0><<<dim3(16,16,1), 256, 0, stream>>>(stateF_s, (u16*)P_s, out, 64, 1,
            0L,0L,1, 524288L,  0L,0L,1, 524288L,  0L,0L,1, 2048L, 0L);
    }
}

// Round 4
// 476.391 us; speedup vs baseline: 1.9536x; 1.1120x over previous
//
#include <hip/hip_runtime.h>
#include <hip/hip_bf16.h>

#define DEVI __device__ __forceinline__

typedef __attribute__((ext_vector_type(8))) short short8;
typedef __attribute__((ext_vector_type(4))) float f32x4;
typedef unsigned short u16;
typedef __attribute__((ext_vector_type(4))) u16 us4;
typedef __attribute__((ext_vector_type(8))) u16 us8;

DEVI u16 bfbits(float x) {
    union { __hip_bfloat16 b; u16 u; } cv;
    cv.b = __float2bfloat16(x);
    return cv.u;
}
DEVI float bff(u16 u) {
    union { u16 u; __hip_bfloat16 b; } cv;
    cv.u = u;
    return __bfloat162float(cv.b);
}

DEVI void gload16(const void* g, void* l) {
    __builtin_amdgcn_global_load_lds(
        (const __attribute__((address_space(1))) unsigned int*)g,
        (__attribute__((address_space(3))) unsigned int*)l, 16, 0, 0);
}

// ---- layouts ----
// SPLIT block: [128 rows][32 k] as u16[8192]: idx = r*64 + (k/8)*16 + (hi?0:8) + k%8, idx ^= (r&7)<<3
// SINGLE block: [128 rows][64 k] as u16[8192]: idx = (r*64 + k) ^ ((r&7)<<3)

DEVI void wsplit(u16* buf, long bb, int r, int kc, float v) {
    const int sw = (r & 7) << 3;
    const int off = r * 64 + ((kc >> 3) << 4) + (kc & 7);
    u16 h = bfbits(v);
    buf[bb + (off ^ sw)] = h;
    buf[bb + ((off + 8) ^ sw)] = bfbits(v - bff(h));
}

DEVI void stage4(u16* L, int r, int c0, float4 v) {
    const int sw = (r & 7) << 3;
    const int kb = c0 >> 3, c4 = c0 & 7;
    float f[4] = {v.x, v.y, v.z, v.w};
    us4 h, l;
#pragma unroll
    for (int j = 0; j < 4; ++j) {
        u16 hh = bfbits(f[j]);
        h[j] = hh;
        l[j] = bfbits(f[j] - bff(hh));
    }
    *(us4*)(L + ((r * 64 + kb * 16 + c4) ^ sw)) = h;
    *(us4*)(L + ((r * 64 + kb * 16 + c4 + 8) ^ sw)) = l;
}

// Generic 128x128-tile GEMM, C = A * B^T, split-bf16 (3 MFMA) fp32 accumulate.
template<int AM, int BMm, int CM, int CAUSAL>
__global__ __launch_bounds__(256) void gemmk(
    const void* __restrict__ Ap, const void* __restrict__ Bp, void* __restrict__ Cp,
    int nKt, int zdiv,
    long aZ0, long aZ1, int aDiv, long aMT,
    long bZ0, long bZ1, int bDiv, long bMT,
    long cZ0, long cZ1, int cDiv, long cP0, long cP1)
{
    const int z = blockIdx.z;
    const int zo = z / zdiv, zi = z - zo * zdiv;
    const int m0 = blockIdx.y * 128, n0 = blockIdx.x * 128;
    if (CAUSAL == 1 && n0 > m0) return;
    int kend = nKt;
    if (CAUSAL == 2) { int ke = (m0 >> 5) + 4; kend = ke < nKt ? ke : nKt; }

    __shared__ u16 LA[8192], LB[8192];
    const int tid = threadIdx.x, w = tid >> 6, lane = tid & 63;
    const int wr = (w >> 1) * 64, wc = (w & 1) * 64, fr = lane & 15, fkb = lane >> 4;

    const u16* Ab = nullptr; const float* Af = nullptr;
    if (AM == 1) Ab = (const u16*)Ap + zo * aZ0 + (long)(zi / aDiv) * aZ1 + (long)(m0 >> 7) * aMT;
    else         Af = (const float*)Ap + zo * aZ0 + (long)(zi / aDiv) * aZ1 + (long)m0 * aMT;
    const u16* Bb = nullptr; const float* Bf = nullptr;
    if (BMm == 1) Bb = (const u16*)Bp + zo * bZ0 + (long)(zi / bDiv) * bZ1 + (long)(n0 >> 7) * bMT;
    else          Bf = (const float*)Bp + zo * bZ0 + (long)(zi / bDiv) * bZ1 + (long)n0 * bMT;

    f32x4 acc[4][4] = {};

    for (int kt = 0; kt < kend; ++kt) {
        if (AM == 1) {
            const char* s = (const char*)(Ab + (long)kt * 8192);
#pragma unroll
            for (int i = 0; i < 4; ++i)
                gload16(s + i * 4096 + w * 1024 + lane * 16, (char*)LA + i * 4096 + w * 1024);
        } else {
#pragma unroll
            for (int i = 0; i < 4; ++i) {
                int idx = i * 256 + tid, r = idx >> 3, c0 = (idx & 7) << 2;
                float4 v = *reinterpret_cast<const float4*>(Af + (long)r * aMT + kt * 32 + c0);
                stage4(LA, r, c0, v);
            }
        }
        if (BMm == 1) {
            const char* s = (const char*)(Bb + (long)kt * 8192);
#pragma unroll
            for (int i = 0; i < 4; ++i)
                gload16(s + i * 4096 + w * 1024 + lane * 16, (char*)LB + i * 4096 + w * 1024);
        } else {
#pragma unroll
            for (int i = 0; i < 4; ++i) {
                int idx = i * 256 + tid, r = idx >> 3, c0 = (idx & 7) << 2;
                float4 v = *reinterpret_cast<const float4*>(Bf + (long)r * bMT + kt * 32 + c0);
                stage4(LB, r, c0, v);
            }
        }
        __syncthreads();

        short8 ah[4], al[4], bh[4], bl[4];
#pragma unroll
        for (int m = 0; m < 4; ++m) {
            int r = wr + m * 16 + fr, sw = (r & 7) << 3, base = r * 64 + fkb * 16;
            ah[m] = *(const short8*)(LA + (base ^ sw));
            al[m] = *(const short8*)(LA + ((base + 8) ^ sw));
        }
#pragma unroll
        for (int n = 0; n < 4; ++n) {
            int r = wc + n * 16 + fr, sw = (r & 7) << 3, base = r * 64 + fkb * 16;
            bh[n] = *(const short8*)(LB + (base ^ sw));
            bl[n] = *(const short8*)(LB + ((base + 8) ^ sw));
        }
#pragma unroll
        for (int m = 0; m < 4; ++m)
#pragma unroll
            for (int n = 0; n < 4; ++n) {
                acc[m][n] = __builtin_amdgcn_mfma_f32_16x16x32_bf16(ah[m], bh[n], acc[m][n], 0, 0, 0);
                acc[m][n] = __builtin_amdgcn_mfma_f32_16x16x32_bf16(ah[m], bl[n], acc[m][n], 0, 0, 0);
                acc[m][n] = __builtin_amdgcn_mfma_f32_16x16x32_bf16(al[m], bh[n], acc[m][n], 0, 0, 0);
            }
        __syncthreads();
    }

    if (CM == 0) {
        float* C = (float*)Cp + zo * cZ0 + (long)(zi / cDiv) * cZ1;
        const long ldc = cP0;
#pragma unroll
        for (int m = 0; m < 4; ++m)
#pragma unroll
            for (int j = 0; j < 4; ++j) {
                long row = m0 + wr + m * 16 + (lane >> 4) * 4 + j;
#pragma unroll
                for (int n = 0; n < 4; ++n)
                    C[row * ldc + n0 + wc + n * 16 + fr] = acc[m][n][j];
            }
    } else {
        u16* C = (u16*)Cp + zo * cZ0 + (long)(zi / cDiv) * cZ1 + (long)(m0 >> 7) * cP0;
#pragma unroll
        for (int n = 0; n < 4; ++n) {
            int colg = n0 + wc + n * 16 + fr;
            long kb_ = (long)(colg >> 5) * cP1;
            int off0 = ((colg >> 3) & 3) * 16 + (colg & 7);
#pragma unroll
            for (int m = 0; m < 4; ++m)
#pragma unroll
                for (int j = 0; j < 4; ++j) {
                    int r = wr + m * 16 + (lane >> 4) * 4 + j;
                    int sw = (r & 7) << 3;
                    float v = acc[m][n][j];
                    u16 h = bfbits(v);
                    C[kb_ + ((r * 64 + off0) ^ sw)] = h;
                    C[kb_ + ((r * 64 + off0 + 8) ^ sw)] = bfbits(v - bff(h));
                }
        }
    }
}

// fp32 [R][2048] row-major -> split-blocked [Rt][64][8192]
__global__ __launch_bounds__(256) void splitk(const float* __restrict__ in, u16* __restrict__ out) {
    const long t = (long)blockIdx.x * 256 + threadIdx.x;
    const int row = (int)(t >> 8), kg = (int)(t & 255);
    const int k0 = kg << 3;
    const float* src = in + (long)row * 2048 + k0;
    float4 a = *(const float4*)src, b = *(const float4*)(src + 4);
    float f[8] = {a.x, a.y, a.z, a.w, b.x, b.y, b.z, b.w};
    us8 h, l;
#pragma unroll
    for (int j = 0; j < 8; ++j) {
        u16 hh = bfbits(f[j]);
        h[j] = hh;
        l[j] = bfbits(f[j] - bff(hh));
    }
    const int Kt = k0 >> 5, kb = kg & 3, r = row & 127, Rt = row >> 7, sw = (r & 7) << 3;
    u16* o = out + ((long)Rt * 64 + Kt) * 8192;
    *(us8*)(o + ((r * 64 + kb * 16) ^ sw)) = h;
    *(us8*)(o + ((r * 64 + kb * 16 + 8) ^ sw)) = l;
}

__global__ __launch_bounds__(256) void split3(const float* __restrict__ Wq, const float* __restrict__ Wk,
                                              const float* __restrict__ Wv, u16* __restrict__ out) {
    const long t = (long)blockIdx.x * 256 + threadIdx.x;
    const int row = (int)(t >> 8), kg = (int)(t & 255);
    const int k0 = kg << 3;
    const float* src;
    if (row < 2048)      src = Wq + (long)row * 2048 + k0;
    else if (row < 3072) src = Wk + (long)(row - 2048) * 2048 + k0;
    else                 src = Wv + (long)(row - 3072) * 2048 + k0;
    float4 a = *(const float4*)src, b = *(const float4*)(src + 4);
    float f[8] = {a.x, a.y, a.z, a.w, b.x, b.y, b.z, b.w};
    us8 h, l;
#pragma unroll
    for (int j = 0; j < 8; ++j) {
        u16 hh = bfbits(f[j]);
        h[j] = hh;
        l[j] = bfbits(f[j] - bff(hh));
    }
    const int Kt = k0 >> 5, kb = kg & 3, r = row & 127, Rt = row >> 7, sw = (r & 7) << 3;
    u16* o = out + ((long)Rt * 64 + Kt) * 8192;
    *(us8*)(o + ((r * 64 + kb * 16) ^ sw)) = h;
    *(us8*)(o + ((r * 64 + kb * 16 + 8) ^ sw)) = l;
}

// RMSNorm + RoPE epilogue. state/k split-blocked; kT/vT single-bf16 blocked.
__global__ __launch_bounds__(256) void qkv_epi(
    const float* __restrict__ qkv, const float* __restrict__ cosb, const float* __restrict__ sinb,
    const float* __restrict__ qw, const float* __restrict__ kw,
    u16* __restrict__ state_s, u16* __restrict__ k_s,
    u16* __restrict__ kT_s, u16* __restrict__ vT_s)
{
    const int bs = blockIdx.x, b = bs >> 10, s = bs & 1023;
    const float* row = qkv + (long)bs * 4096;
    const int w = threadIdx.x >> 6, lane = threadIdx.x & 63;
    const float clo = cosb[(long)bs * 128 + lane], chi = cosb[(long)bs * 128 + 64 + lane];
    const float slo = sinb[(long)bs * 128 + lane], shi = sinb[(long)bs * 128 + 64 + lane];
    const int Mt = s >> 7, r = s & 127;
    const float qwl = qw[lane], qwh = qw[lane + 64], kwl = kw[lane], kwh = kw[lane + 64];

    for (int h = w; h < 16; h += 4) {
        float xlo = row[h * 128 + lane], xhi = row[h * 128 + 64 + lane];
        float ss = xlo * xlo + xhi * xhi;
#pragma unroll
        for (int o = 32; o; o >>= 1) ss += __shfl_xor(ss, o);
        float rr = 1.0f / sqrtf(ss * (1.0f / 128.0f) + 1e-6f);
        float ylo = xlo * rr * qwl, yhi = xhi * rr * qwh;
        float olo = ylo * clo - yhi * slo;
        float ohi = yhi * chi + ylo * shi;
        long zb = (long)(b * 16 + h) * 262144 + (long)Mt * 32768;
        wsplit(state_s, zb + (long)(lane >> 5) * 8192, r, lane & 31, olo);
        wsplit(state_s, zb + (long)(2 + (lane >> 5)) * 8192, r, lane & 31, ohi);
    }
    for (int kv = w; kv < 8; kv += 4) {
        float xlo = row[2048 + kv * 128 + lane], xhi = row[2048 + kv * 128 + 64 + lane];
        float ss = xlo * xlo + xhi * xhi;
#pragma unroll
        for (int o = 32; o; o >>= 1) ss += __shfl_xor(ss, o);
        float rr = 1.0f / sqrtf(ss * (1.0f / 128.0f) + 1e-6f);
        float ylo = xlo * rr * kwl, yhi = xhi * rr * kwh;
        float olo = ylo * clo - yhi * slo;
        float ohi = yhi * chi + ylo * shi;
        long zb = (long)(b * 8 + kv) * 262144 + (long)Mt * 32768;
        wsplit(k_s, zb + (long)(lane >> 5) * 8192, r, lane & 31, olo);
        wsplit(k_s, zb + (long)(2 + (lane >> 5)) * 8192, r, lane & 31, ohi);
        long tb = (long)(b * 8 + kv) * 131072 + (long)(s >> 6) * 8192;
        const int c = s & 63, sw = (lane & 7) << 3;
        kT_s[tb + ((lane * 64 + c) ^ sw)] = bfbits(olo);
        kT_s[tb + (((lane + 64) * 64 + c) ^ sw)] = bfbits(ohi);
    }
    for (int kv = w; kv < 8; kv += 4) {
        float xlo = row[3072 + kv * 128 + lane], xhi = row[3072 + kv * 128 + 64 + lane];
        long tb = (long)(b * 8 + kv) * 131072 + (long)(s >> 6) * 8192;
        const int c = s & 63, sw = (lane & 7) << 3;
        vT_s[tb + ((lane * 64 + c) ^ sw)] = bfbits(xlo);
        vT_s[tb + (((lane + 64) * 64 + c) ^ sw)] = bfbits(xhi);
    }
}

// Fused Hopfield step v2 (t<2). grid (z=32, qt64=16), 256 threads.
// 64 q-rows per block (16 per wave, held in registers), 64-row j-steps.
// No max subtraction (scores bounded); single end-of-loop row-sum reduce.
__global__ __launch_bounds__(256) void hopstep(
    const u16* __restrict__ Sin, const u16* __restrict__ Ks,
    const u16* __restrict__ KTs, const float* __restrict__ lb,
    u16* __restrict__ Sout)
{
    const int z = blockIdx.x, qt = blockIdx.y;     // qt: 64-row q-tile, 0..15
    const int b = z >> 4, h = z & 15;
    const int zp = b * 8 + (h >> 1);
    const float sb = 0.08838834764831845f * __expf(lb[0]);

    __shared__ u16 LK[16384];     // K j-tile: 4 ks x [64 rows][64] split  (32 KB)
    __shared__ u16 LV[2][8192];   // kT sblock double buffer (2 x 16 KB)
    __shared__ u16 LP[4096];      // P tile 64x64 single bf16 (8 KB)

    const int tid = threadIdx.x, w = tid >> 6, lane = tid & 63;
    const int fr = lane & 15, fkb = lane >> 4;

    // ---- Q into registers (split) ----
    const int Mt = qt >> 1;
    const int qr = (qt & 1) * 64 + w * 16 + fr;     // row within Q sblock
    const int qsw = (qr & 7) << 3;
    const u16* Qg = Sin + (long)z * 262144 + (long)Mt * 32768;
    short8 qh[4], ql[4];
#pragma unroll
    for (int ks = 0; ks < 4; ++ks) {
        int base = qr * 64 + fkb * 16;
        qh[ks] = *(const short8*)(Qg + ks * 8192 + (base ^ qsw));
        ql[ks] = *(const short8*)(Qg + ks * 8192 + ((base + 8) ^ qsw));
    }

    const char* Kz  = (const char*)(Ks + (long)zp * 262144);
    const char* KTz = (const char*)(KTs + (long)zp * 131072);
    const int jend = qt + 1;

    f32x4 po[8] = {};
    float lsum[4] = {0.f, 0.f, 0.f, 0.f};

    // prologue: stage K(jt=0) and V(jt=0, buf 0)
    {
        const char* kb = Kz + (long)(0 >> 1) * 65536 + (0 & 1) * 8192;
#pragma unroll
        for (int ks = 0; ks < 4; ++ks)
#pragma unroll
            for (int i = 0; i < 2; ++i)
                gload16(kb + ks * 16384 + i * 4096 + tid * 16, (char*)LK + ks * 8192 + i * 4096 + tid * 16);
#pragma unroll
        for (int i = 0; i < 4; ++i)
            gload16(KTz + i * 4096 + tid * 16, (char*)LV[0] + i * 4096 + tid * 16);
    }

#pragma unroll 1
    for (int jt = 0; jt < jend; ++jt) {
        __syncthreads();   // B: LK(jt), LV[jt&1] staged (vmcnt drained); prev LP reads done

        const bool diag = (jt == qt);
        const int nmax = diag ? (w + 1) : 4;

        // QK^T: scores for this wave's 16 q-rows x 64 j-cols
        f32x4 ps[4] = {};
#pragma unroll 1
        for (int n = 0; n < nmax; ++n) {
            int rj = n * 16 + fr, sw = (rj & 7) << 3, base = rj * 64 + fkb * 16;
#pragma unroll
            for (int ks = 0; ks < 4; ++ks) {
                short8 bh = *(const short8*)(LK + ks * 4096 + (base ^ sw));
                short8 bl = *(const short8*)(LK + ks * 4096 + ((base + 8) ^ sw));
                ps[n] = __builtin_amdgcn_mfma_f32_16x16x32_bf16(qh[ks], bh, ps[n], 0, 0, 0);
                ps[n] = __builtin_amdgcn_mfma_f32_16x16x32_bf16(qh[ks], bl, ps[n], 0, 0, 0);
                ps[n] = __builtin_amdgcn_mfma_f32_16x16x32_bf16(ql[ks], bh, ps[n], 0, 0, 0);
            }
        }

        // scale + mask + exp (no max subtraction; scores bounded) + LP write
        const int qloc = w * 16 + fkb * 4;   // + jj = local q row
#pragma unroll
        for (int n = 0; n < 4; ++n) {
            int jcol = n * 16 + fr;
#pragma unroll
            for (int jj = 0; jj < 4; ++jj) {
                float p = 0.f;
                if (n < nmax) {
                    bool msk = diag && (jcol > qloc + jj);
                    p = msk ? 0.f : __expf(ps[n][jj] * sb);
                }
                lsum[jj] += p;
                int rq = qloc + jj;
                LP[(rq * 64 + jcol) ^ ((rq & 7) << 3)] = bfbits(p);
            }
        }

        __syncthreads();   // C: LP visible; all LK reads complete

        // issue next-tile stages (LK, LV[^1]) before PV MFMAs
        if (jt + 1 < jend) {
            const char* kb = Kz + (long)((jt + 1) >> 1) * 65536 + ((jt + 1) & 1) * 8192;
#pragma unroll
            for (int ks = 0; ks < 4; ++ks)
#pragma unroll
                for (int i = 0; i < 2; ++i)
                    gload16(kb + ks * 16384 + i * 4096 + tid * 16, (char*)LK + ks * 8192 + i * 4096 + tid * 16);
            char* lv = (char*)LV[(jt + 1) & 1];
#pragma unroll
            for (int i = 0; i < 4; ++i)
                gload16(KTz + (long)(jt + 1) * 16384 + i * 4096 + tid * 16, lv + i * 4096 + tid * 16);
        }

        // PV: po[q, d] += P[q, j] * V[j, d]
        const u16* lvb = LV[jt & 1];
#pragma unroll
        for (int s2 = 0; s2 < 2; ++s2) {
            int rq = w * 16 + fr;
            short8 pa = *(const short8*)(LP + ((rq * 64 + s2 * 32 + fkb * 8) ^ ((rq & 7) << 3)));
#pragma unroll
            for (int n = 0; n < 8; ++n) {
                int rd = n * 16 + fr;
                short8 vb = *(const short8*)(lvb + ((rd * 64 + s2 * 32 + fkb * 8) ^ ((rd & 7) << 3)));
                po[n] = __builtin_amdgcn_mfma_f32_16x16x32_bf16(pa, vb, po[n], 0, 0, 0);
            }
        }
    }

    // epilogue: row-sum reduce, normalize, exact-split write
#pragma unroll
    for (int jj = 0; jj < 4; ++jj) {
        float v = lsum[jj];
        v += __shfl_xor(v, 1);
        v += __shfl_xor(v, 2);
        v += __shfl_xor(v, 4);
        v += __shfl_xor(v, 8);
        lsum[jj] = 1.0f / v;
    }
    u16* outp = Sout + (long)z * 262144;
#pragma unroll
    for (int jj = 0; jj < 4; ++jj) {
        int qrow = qt * 64 + w * 16 + fkb * 4 + jj;
        int Mo = qrow >> 7, r = qrow & 127, sw = (r & 7) << 3;
        long mb = (long)Mo * 32768;
#pragma unroll
        for (int n = 0; n < 8; ++n) {
            int d = n * 16 + fr;
            long base = mb + (long)(d >> 5) * 8192;
            int off0 = ((d >> 3) & 3) * 16 + (d & 7);
            float v = po[n][jj] * lsum[jj];
            u16 hh = bfbits(v);
            outp[base + ((r * 64 + off0) ^ sw)] = hh;
            outp[base + ((r * 64 + off0 + 8) ^ sw)] = bfbits(v - bff(hh));
        }
    }
}

// Final softmax: raw scores (attn) -> normalized fp32 full row (zeros past causal)
// + single-bf16 blocked P_s (packed causal: z*72*8192 + qt*(qt+1)*8192).
__global__ __launch_bounds__(256) void softmaxF(
    float* __restrict__ sc, const float* __restrict__ lb, u16* __restrict__ P_s)
{
    const int row = blockIdx.x;
    const long z = blockIdx.y;
    float* rp = sc + (z * 1024 + row) * 1024;
    const int W = ((row >> 7) + 1) << 7, qt = row >> 7;
    const int tid = threadIdx.x, w = tid >> 6, lane = tid & 63;
    const float sb = 0.08838834764831845f * expf(lb[0]);
    const int c0 = tid * 4;
    const bool act = c0 < W;
    float x0 = -3e38f, x1 = -3e38f, x2 = -3e38f, x3 = -3e38f;
    if (act) {
        float4 v = *reinterpret_cast<const float4*>(rp + c0);
        x0 = (c0 + 0 <= row) ? v.x * sb : -3e38f;
        x1 = (c0 + 1 <= row) ? v.y * sb : -3e38f;
        x2 = (c0 + 2 <= row) ? v.z * sb : -3e38f;
        x3 = (c0 + 3 <= row) ? v.w * sb : -3e38f;
    }
    __shared__ float red[8];
    float mx = fmaxf(fmaxf(x0, x1), fmaxf(x2, x3));
#pragma unroll
    for (int o = 32; o; o >>= 1) mx = fmaxf(mx, __shfl_xor(mx, o));
    if (!lane) red[w] = mx;
    __syncthreads();
    mx = fmaxf(fmaxf(red[0], red[1]), fmaxf(red[2], red[3]));

    float e0 = expf(x0 - mx), e1 = expf(x1 - mx), e2 = expf(x2 - mx), e3 = expf(x3 - mx);
    float sm = e0 + e1 + e2 + e3;
#pragma unroll
    for (int o = 32; o; o >>= 1) sm += __shfl_xor(sm, o);
    if (!lane) red[4 + w] = sm;
    __syncthreads();
    sm = red[4] + red[5] + red[6] + red[7];
    float inv = 1.0f / sm;

    float p0 = e0 * inv, p1 = e1 * inv, p2 = e2 * inv, p3 = e3 * inv;
    float4 o4; o4.x = p0; o4.y = p1; o4.z = p2; o4.w = p3;
    *reinterpret_cast<float4*>(rp + c0) = o4;
    if (act) {
        const int r = row & 127, sw = (r & 7) << 3;
        long idx = z * 589824 + (long)qt * (qt + 1) * 8192 + (long)(c0 >> 6) * 8192
                 + ((r * 64 + (c0 & 63)) ^ sw);
        us4 pw; pw[0] = bfbits(p0); pw[1] = bfbits(p1); pw[2] = bfbits(p2); pw[3] = bfbits(p3);
        *(us4*)(P_s + idx) = pw;
    }
}

// Final PV: stateF = P . V (single x single), split-blocked output for out-proj.
// grid (qt=8, z=32).
__global__ __launch_bounds__(256) void pvfin(
    const u16* __restrict__ P_s, const u16* __restrict__ vT_s, u16* __restrict__ stateF)
{
    const int qt = blockIdx.x, z = blockIdx.y;
    const int b = z >> 4, h = z & 15;
    const int zp = b * 8 + (h >> 1);
    __shared__ u16 LA[8192], LB[8192];
    const int tid = threadIdx.x, w = tid >> 6, lane = tid & 63;
    const int fr = lane & 15, fkb = lane >> 4;
    const int wr = w * 32;

    const char* Pa = (const char*)(P_s + (long)z * 589824 + (long)qt * (qt + 1) * 8192);
    const char* Vz = (const char*)(vT_s + (long)zp * 131072);
    const int nj = 2 * qt + 2;

    f32x4 po[2][8] = {};
#pragma unroll 1
    for (int jsb = 0; jsb < nj; ++jsb) {
        __syncthreads();
#pragma unroll
        for (int i = 0; i < 4; ++i) {
            gload16(Pa + (long)jsb * 16384 + i * 4096 + w * 1024 + lane * 16,
                    (char*)LA + i * 4096 + w * 1024);
            gload16(Vz + (long)jsb * 16384 + i * 4096 + w * 1024 + lane * 16,
                    (char*)LB + i * 4096 + w * 1024);
        }
        __syncthreads();
#pragma unroll
        for (int s2 = 0; s2 < 2; ++s2) {
            short8 pa[2];
#pragma unroll
            for (int m = 0; m < 2; ++m) {
                int r = wr + m * 16 + fr;
                pa[m] = *(const short8*)(LA + ((r * 64 + s2 * 32 + fkb * 8) ^ ((r & 7) << 3)));
            }
#pragma unroll
            for (int n = 0; n < 8; ++n) {
                int r = n * 16 + fr;
                short8 vb = *(const short8*)(LB + ((r * 64 + s2 * 32 + fkb * 8) ^ ((r & 7) << 3)));
#pragma unroll
                for (int m = 0; m < 2; ++m)
                    po[m][n] = __builtin_amdgcn_mfma_f32_16x16x32_bf16(pa[m], vb, po[m][n], 0, 0, 0);
            }
        }
    }
    // split write to stateF [16 Mt][64 Kt][8192]
#pragma unroll
    for (int m = 0; m < 2; ++m)
#pragma unroll
        for (int j = 0; j < 4; ++j) {
            int r = wr + m * 16 + fkb * 4 + j, sw = (r & 7) << 3;
#pragma unroll
            for (int n = 0; n < 8; ++n) {
                int colg = n * 16 + fr;
                long base = (long)(b * 8 + qt) * 524288 + (long)(h * 4 + (colg >> 5)) * 8192;
                int off0 = ((colg >> 3) & 3) * 16 + (colg & 7);
                float v = po[m][n][j];
                u16 hh = bfbits(v);
                stateF[base + ((r * 64 + off0) ^ sw)] = hh;
                stateF[base + ((r * 64 + off0 + 8) ^ sw)] = bfbits(v - bff(hh));
            }
        }
}

extern "C" void kernel_launch(void* const* d_in, const int* in_sizes, int n_in,
                              void* d_out, int out_size, void* d_ws, size_t ws_size,
                              hipStream_t stream)
{
    const float* hs   = (const float*)d_in[0];
    const float* cosb = (const float*)d_in[1];
    const float* sinb = (const float*)d_in[2];
    const float* Wq   = (const float*)d_in[4];
    const float* Wk   = (const float*)d_in[5];
    const float* Wv   = (const float*)d_in[6];
    const float* Wo   = (const float*)d_in[7];
    const float* qw   = (const float*)d_in[8];
    const float* kw   = (const float*)d_in[9];
    const float* lb   = (const float*)d_in[10];

    float* out  = (float*)d_out;
    float* attn = out + 4194304;

    char* ws = (char*)d_ws;
    const bool full = ws_size >= 134217728ull;

    u16 *Wqkv_s = nullptr, *Wo_s = nullptr, *hs_s = nullptr;
    u16 *state_s, *state2_s, *stateF_s, *k_s, *kT_s, *vT_s, *P_s;
    float* qkv;
    if (full) {
        Wqkv_s   = (u16*)(ws);                       // 33.5M, dead after QKV gemm
        hs_s     = (u16*)(ws + 33554432L);           // 16.8M, dead after QKV gemm
        P_s      = (u16*)(ws);                       // 37.75M, alias (used from t=2 softmax)
        Wo_s     = (u16*)(ws + 50331648L);
        qkv      = (float*)(ws + 67108864L);         // dead after epi
        state2_s = (u16*)(ws + 67108864L);
        stateF_s = (u16*)(ws + 83886080L);
        state_s  = (u16*)(ws + 100663296L);
        k_s      = (u16*)(ws + 117440512L);
        kT_s     = (u16*)(ws + 125829120L);
        vT_s     = (u16*)(ws + 130023424L);
    } else {
        qkv      = (float*)ws;
        state2_s = (u16*)ws;
        stateF_s = (u16*)(ws + 16777216L);
        state_s  = (u16*)(ws + 33554432L);
        k_s      = (u16*)(ws + 50331648L);
        kT_s     = (u16*)(ws + 58720256L);
        vT_s     = (u16*)(ws + 62914560L);
        P_s      = (u16*)(ws + 67108864L);
    }

    if (full) {
        splitk<<<2048, 256, 0, stream>>>(hs, hs_s);
        split3<<<4096, 256, 0, stream>>>(Wq, Wk, Wv, Wqkv_s);
        splitk<<<2048, 256, 0, stream>>>(Wo, Wo_s);
        gemmk<1,1,0,0><<<dim3(32,16,1), 256, 0, stream>>>(hs_s, Wqkv_s, qkv, 64, 1,
            0L,0L,1, 524288L,  0L,0L,1, 524288L,  0L,0L,1, 4096L, 0L);
    } else {
        gemmk<0,0,0,0><<<dim3(16,16,1), 256, 0, stream>>>(hs, Wq, qkv, 64, 1,
            0L,0L,1, 2048L,  0L,0L,1, 2048L,  0L,0L,1, 4096L, 0L);
        gemmk<0,0,0,0><<<dim3(8,16,1), 256, 0, stream>>>(hs, Wk, qkv + 2048, 64, 1,
            0L,0L,1, 2048L,  0L,0L,1, 2048L,  0L,0L,1, 4096L, 0L);
        gemmk<0,0,0,0><<<dim3(8,16,1), 256, 0, stream>>>(hs, Wv, qkv + 3072, 64, 1,
            0L,0L,1, 2048L,  0L,0L,1, 2048L,  0L,0L,1, 4096L, 0L);
    }

    qkv_epi<<<2048, 256, 0, stream>>>(qkv, cosb, sinb, qw, kw, state_s, k_s, kT_s, vT_s);

    // t = 0, 1 fused (grid x = z for XCD L2 locality of K/kT)
    hopstep<<<dim3(32,16), 256, 0, stream>>>(state_s, k_s, kT_s, lb, state2_s);
    hopstep<<<dim3(32,16), 256, 0, stream>>>(state2_s, k_s, kT_s, lb, state_s);

    // t = 2: raw scores -> softmax (fp32 out + bf16 P) -> PV
    gemmk<1,1,0,1><<<dim3(8,8,32), 256, 0, stream>>>(state_s, k_s, attn, 4, 16,
        4194304L, 262144L, 1, 32768L,
        2097152L, 262144L, 2, 32768L,
        16777216L, 1048576L, 1, 1024L, 0L);
    softmaxF<<<dim3(1024,32), 256, 0, stream>>>(attn, lb, P_s);
    pvfin<<<dim3(8,32), 256, 0, stream>>>(P_s, vT_s, stateF_s);

    // out = stateF . Wo^T
    if (full) {
        gemmk<1,1,0,0><<<dim3(16,16,1), 256, 0, stream>>>(stateF_s, Wo_s, out, 64, 1,
            0L,0L,1, 524288L,  0L,0L,1, 524288L,  0L,0L,1, 2048L, 0L);
    } else {
        gemmk<1,0,0,0><<<dim3(16,16,1), 256, 0, stream>>>(stateF_s, Wo, out, 64, 1,
            0L,0L,1, 524288L,  0L,0L,1, 2048L,  0L,0L,1, 2048L, 0L);
    }
}

// Round 5
// 315.680 us; speedup vs baseline: 2.9482x; 1.5091x over previous
//
#include <hip/hip_runtime.h>

#define DEVI __device__ __forceinline__

typedef __attribute__((ext_vector_type(8))) short short8;
typedef __attribute__((ext_vector_type(4))) float f32x4;
typedef unsigned short u16;
typedef __attribute__((ext_vector_type(4))) u16 us4;
typedef __attribute__((ext_vector_type(8))) u16 us8;

#define MFMA16(a, b, c) __builtin_amdgcn_mfma_f32_16x16x32_f16(a, b, c, 0, 0, 0)

DEVI u16 hbits(float x) {
    union { _Float16 h; u16 u; } cv;
    cv.h = (_Float16)x;
    return cv.u;
}

DEVI void gload16(const void* g, void* l) {
    __builtin_amdgcn_global_load_lds(
        (const __attribute__((address_space(1))) unsigned int*)g,
        (__attribute__((address_space(3))) unsigned int*)l, 16, 0, 0);
}

// ---- layout ----
// fp16 SINGLE block: [128 rows][64 k] as u16[8192] (16 KB):
//   idx = (r*64 + k) ^ ((r&7)<<3)   (XOR swizzle, bank-conflict-free ds_read_b128)
// Buffers are [Mt][Kt] grids of such blocks.

// fp32 [rows][2048] row-major -> fp16 blocked [Rt][32][8192]
__global__ __launch_bounds__(256) void cvtk(const float* __restrict__ in, u16* __restrict__ out) {
    const long t = (long)blockIdx.x * 256 + threadIdx.x;
    const int row = (int)(t >> 8), kg = (int)(t & 255);
    const int k0 = kg << 3;
    const float* src = in + (long)row * 2048 + k0;
    float4 a = *(const float4*)src, b = *(const float4*)(src + 4);
    float f[8] = {a.x, a.y, a.z, a.w, b.x, b.y, b.z, b.w};
    us8 h;
#pragma unroll
    for (int j = 0; j < 8; ++j) h[j] = hbits(f[j]);
    const int Kt = k0 >> 6, c = k0 & 63, r = row & 127, Rt = row >> 7, sw = (r & 7) << 3;
    *(us8*)(out + ((long)Rt * 32 + Kt) * 8192 + ((r * 64 + c) ^ sw)) = h;
}

// Wq(2048) | Wk(1024) | Wv(1024) rows -> one blocked buffer [32 Rt][32 Kt]
__global__ __launch_bounds__(256) void cvt3(const float* __restrict__ Wq, const float* __restrict__ Wk,
                                            const float* __restrict__ Wv, u16* __restrict__ out) {
    const long t = (long)blockIdx.x * 256 + threadIdx.x;
    const int row = (int)(t >> 8), kg = (int)(t & 255);
    const int k0 = kg << 3;
    const float* src;
    if (row < 2048)      src = Wq + (long)row * 2048 + k0;
    else if (row < 3072) src = Wk + (long)(row - 2048) * 2048 + k0;
    else                 src = Wv + (long)(row - 3072) * 2048 + k0;
    float4 a = *(const float4*)src, b = *(const float4*)(src + 4);
    float f[8] = {a.x, a.y, a.z, a.w, b.x, b.y, b.z, b.w};
    us8 h;
#pragma unroll
    for (int j = 0; j < 8; ++j) h[j] = hbits(f[j]);
    const int Kt = k0 >> 6, c = k0 & 63, r = row & 127, Rt = row >> 7, sw = (r & 7) << 3;
    *(us8*)(out + ((long)Rt * 32 + Kt) * 8192 + ((r * 64 + c) ^ sw)) = h;
}

// 128x128-tile GEMM, C = A * B^T (fp16 operands, fp32 accum/out), BK=64.
// A/B are fp16 blocked [Mt][nKt][8192]; aMT/bMT = nKt*8192 (u16 stride per Mt).
// CAUSAL==1: skip blocks with n0 > m0.
template<int CAUSAL>
__global__ __launch_bounds__(256) void gemmk(
    const u16* __restrict__ Ap, const u16* __restrict__ Bp, float* __restrict__ Cp,
    int nKt, int zdiv,
    long aZ0, long aZ1, int aDiv, long aMT,
    long bZ0, long bZ1, int bDiv, long bMT,
    long cZ0, long cZ1, int cDiv, long ldc)
{
    const int z = blockIdx.z;
    const int zo = z / zdiv, zi = z - zo * zdiv;
    const int m0 = blockIdx.y * 128, n0 = blockIdx.x * 128;
    if (CAUSAL == 1 && n0 > m0) return;

    __shared__ u16 LA[8192], LB[8192];
    const int tid = threadIdx.x, w = tid >> 6, lane = tid & 63;
    const int wr = (w >> 1) * 64, wc = (w & 1) * 64, fr = lane & 15, fkb = lane >> 4;

    const u16* Ab = Ap + zo * aZ0 + (long)(zi / aDiv) * aZ1 + (long)(m0 >> 7) * aMT;
    const u16* Bb = Bp + zo * bZ0 + (long)(zi / bDiv) * bZ1 + (long)(n0 >> 7) * bMT;

    f32x4 acc[4][4] = {};

    for (int kt = 0; kt < nKt; ++kt) {
        const char* sa = (const char*)(Ab + (long)kt * 8192);
        const char* sb_ = (const char*)(Bb + (long)kt * 8192);
#pragma unroll
        for (int i = 0; i < 4; ++i) {
            gload16(sa + i * 4096 + w * 1024 + lane * 16, (char*)LA + i * 4096 + w * 1024);
            gload16(sb_ + i * 4096 + w * 1024 + lane * 16, (char*)LB + i * 4096 + w * 1024);
        }
        __syncthreads();

        short8 av[4][2], bv[4][2];
#pragma unroll
        for (int m = 0; m < 4; ++m) {
            int r = wr + m * 16 + fr, sw = (r & 7) << 3;
#pragma unroll
            for (int ks = 0; ks < 2; ++ks)
                av[m][ks] = *(const short8*)(LA + ((r * 64 + ks * 32 + fkb * 8) ^ sw));
        }
#pragma unroll
        for (int n = 0; n < 4; ++n) {
            int r = wc + n * 16 + fr, sw = (r & 7) << 3;
#pragma unroll
            for (int ks = 0; ks < 2; ++ks)
                bv[n][ks] = *(const short8*)(LB + ((r * 64 + ks * 32 + fkb * 8) ^ sw));
        }
#pragma unroll
        for (int ks = 0; ks < 2; ++ks)
#pragma unroll
            for (int m = 0; m < 4; ++m)
#pragma unroll
                for (int n = 0; n < 4; ++n)
                    acc[m][n] = MFMA16(av[m][ks], bv[n][ks], acc[m][n]);
        __syncthreads();
    }

    float* C = Cp + zo * cZ0 + (long)(zi / cDiv) * cZ1;
#pragma unroll
    for (int m = 0; m < 4; ++m)
#pragma unroll
        for (int j = 0; j < 4; ++j) {
            long row = m0 + wr + m * 16 + fkb * 4 + j;
#pragma unroll
            for (int n = 0; n < 4; ++n)
                C[row * ldc + n0 + wc + n * 16 + fr] = acc[m][n][j];
        }
}

// RMSNorm + RoPE epilogue (reads fp32 qkv). Writes fp16 blocked:
// state_s [z][8 Mt][2 Kt], k_s [zp][8 Mt][2 Kt], kT_s/vT_s [zp][16 Kt(s)][128 d][64 s].
__global__ __launch_bounds__(256) void qkv_epi(
    const float* __restrict__ qkv, const float* __restrict__ cosb, const float* __restrict__ sinb,
    const float* __restrict__ qw, const float* __restrict__ kw,
    u16* __restrict__ state_s, u16* __restrict__ k_s,
    u16* __restrict__ kT_s, u16* __restrict__ vT_s)
{
    const int bs = blockIdx.x, b = bs >> 10, s = bs & 1023;
    const float* row = qkv + (long)bs * 4096;
    const int w = threadIdx.x >> 6, lane = threadIdx.x & 63;
    const float clo = cosb[(long)bs * 128 + lane], chi = cosb[(long)bs * 128 + 64 + lane];
    const float slo = sinb[(long)bs * 128 + lane], shi = sinb[(long)bs * 128 + 64 + lane];
    const int Mt = s >> 7, r = s & 127, sw = (r & 7) << 3;
    const float qwl = qw[lane], qwh = qw[lane + 64], kwl = kw[lane], kwh = kw[lane + 64];
    const int swl = (lane & 7) << 3;

    for (int h = w; h < 16; h += 4) {
        float xlo = row[h * 128 + lane], xhi = row[h * 128 + 64 + lane];
        float ss = xlo * xlo + xhi * xhi;
#pragma unroll
        for (int o = 32; o; o >>= 1) ss += __shfl_xor(ss, o);
        float rr = 1.0f / sqrtf(ss * (1.0f / 128.0f) + 1e-6f);
        float ylo = xlo * rr * qwl, yhi = xhi * rr * qwh;
        float olo = ylo * clo - yhi * slo;
        float ohi = yhi * chi + ylo * shi;
        u16* dst = state_s + (long)(b * 16 + h) * 131072 + (long)Mt * 16384;
        dst[(r * 64 + lane) ^ sw] = hbits(olo);
        dst[8192 + ((r * 64 + lane) ^ sw)] = hbits(ohi);
    }
    for (int kv = w; kv < 8; kv += 4) {
        float xlo = row[2048 + kv * 128 + lane], xhi = row[2048 + kv * 128 + 64 + lane];
        float ss = xlo * xlo + xhi * xhi;
#pragma unroll
        for (int o = 32; o; o >>= 1) ss += __shfl_xor(ss, o);
        float rr = 1.0f / sqrtf(ss * (1.0f / 128.0f) + 1e-6f);
        float ylo = xlo * rr * kwl, yhi = xhi * rr * kwh;
        float olo = ylo * clo - yhi * slo;
        float ohi = yhi * chi + ylo * shi;
        const long zp = (long)(b * 8 + kv);
        u16* dst = k_s + zp * 131072 + (long)Mt * 16384;
        dst[(r * 64 + lane) ^ sw] = hbits(olo);
        dst[8192 + ((r * 64 + lane) ^ sw)] = hbits(ohi);
        u16* dT = kT_s + zp * 131072 + (long)(s >> 6) * 8192;
        const int c = s & 63;
        dT[(lane * 64 + c) ^ swl] = hbits(olo);
        dT[((lane + 64) * 64 + c) ^ swl] = hbits(ohi);
    }
    for (int kv = w; kv < 8; kv += 4) {
        float xlo = row[3072 + kv * 128 + lane], xhi = row[3072 + kv * 128 + 64 + lane];
        u16* dT = vT_s + (long)(b * 8 + kv) * 131072 + (long)(s >> 6) * 8192;
        const int c = s & 63;
        dT[(lane * 64 + c) ^ swl] = hbits(xlo);
        dT[((lane + 64) * 64 + c) ^ swl] = hbits(xhi);
    }
}

// Fused Hopfield step (t<2), fp16. grid 512 blocks: z = bid&31, qt = balance(bid>>5).
// 64 q-rows/block (16/wave in registers); 64-row j-steps; shifted exp (no max-sub).
__global__ __launch_bounds__(256) void hopstep(
    const u16* __restrict__ Sin, const u16* __restrict__ Ks,
    const u16* __restrict__ KTs, const float* __restrict__ lb,
    u16* __restrict__ Sout)
{
    const int bid = blockIdx.x;
    const int z = bid & 31;
    const int g = bid >> 5;
    const int qt = (g < 8) ? g : 23 - g;          // pair (g, g+8) -> qt sums constant
    const int b = z >> 4, h = z & 15;
    const int zp = b * 8 + (h >> 1);
    const float sb = 0.08838834764831845f * __expf(lb[0]);

    __shared__ u16 LK[8192];      // K j-tile [2 Kt][64 rows][64]  (16 KB)
    __shared__ u16 LV[2][8192];   // kT s-block double buffer (2 x 16 KB)
    __shared__ u16 LP[4096];      // P tile 64x64 fp16 (8 KB)

    const int tid = threadIdx.x, w = tid >> 6, lane = tid & 63;
    const int fr = lane & 15, fkb = lane >> 4;

    // Q into registers
    const int qrow = qt * 64 + w * 16 + fr;
    const int qMt = qrow >> 7, qr = qrow & 127, qsw = (qr & 7) << 3;
    const u16* Qg = Sin + (long)z * 131072 + (long)qMt * 16384;
    short8 qv[4];
#pragma unroll
    for (int ks = 0; ks < 4; ++ks)
        qv[ks] = *(const short8*)(Qg + (ks >> 1) * 8192 + ((qr * 64 + (ks & 1) * 32 + fkb * 8) ^ qsw));

    const char* Kzb = (const char*)(Ks + (long)zp * 131072);
    const char* KTz = (const char*)(KTs + (long)zp * 131072);
    const int jend = qt + 1;

    f32x4 po[8] = {};
    float lsum[4] = {0.f, 0.f, 0.f, 0.f};

    // prologue: stage K(jt=0) and V(jt=0)
#pragma unroll
    for (int i = 0; i < 4; ++i) {
        gload16(Kzb + (i >> 1) * 16384 + (i & 1) * 4096 + w * 1024 + lane * 16,
                (char*)LK + i * 4096 + w * 1024);
        gload16(KTz + i * 4096 + w * 1024 + lane * 16, (char*)LV[0] + i * 4096 + w * 1024);
    }

#pragma unroll 1
    for (int jt = 0; jt < jend; ++jt) {
        __syncthreads();   // LK(jt), LV[jt&1] ready; previous LP reads done

        const bool diag = (jt == qt);
        const int nmax = diag ? (w + 1) : 4;

        f32x4 ps[4] = {};
#pragma unroll 1
        for (int n = 0; n < nmax; ++n) {
            int rj = n * 16 + fr, swj = (rj & 7) << 3;
#pragma unroll
            for (int ks = 0; ks < 4; ++ks) {
                short8 bk = *(const short8*)(LK + (ks >> 1) * 4096 +
                                             ((rj * 64 + (ks & 1) * 32 + fkb * 8) ^ swj));
                ps[n] = MFMA16(qv[ks], bk, ps[n]);
            }
        }

        // shifted exp (cancels in normalization; keeps p in fp16 range) + LP write
        const int qloc = w * 16 + fkb * 4;
#pragma unroll
        for (int n = 0; n < 4; ++n) {
            int jcol = n * 16 + fr;
#pragma unroll
            for (int jj = 0; jj < 4; ++jj) {
                float p = 0.f;
                if (n < nmax) {
                    bool msk = diag && (jcol > qloc + jj);
                    p = msk ? 0.f : __expf(ps[n][jj] * sb - 4.0f);
                }
                lsum[jj] += p;
                int rq = qloc + jj;
                LP[(rq * 64 + jcol) ^ ((rq & 7) << 3)] = hbits(p);
            }
        }

        __syncthreads();   // LP visible; LK reads complete

        if (jt + 1 < jend) {
            const int jn = jt + 1;
#pragma unroll
            for (int i = 0; i < 4; ++i) {
                gload16(Kzb + (long)((jn >> 1) * 2 + (i >> 1)) * 16384 + (jn & 1) * 8192 +
                            (i & 1) * 4096 + w * 1024 + lane * 16,
                        (char*)LK + i * 4096 + w * 1024);
                gload16(KTz + (long)jn * 16384 + i * 4096 + w * 1024 + lane * 16,
                        (char*)LV[jn & 1] + i * 4096 + w * 1024);
            }
        }

        // PV
        const u16* lvb = LV[jt & 1];
        const int rq = w * 16 + fr;
#pragma unroll
        for (int ks2 = 0; ks2 < 2; ++ks2) {
            short8 pa = *(const short8*)(LP + ((rq * 64 + ks2 * 32 + fkb * 8) ^ ((rq & 7) << 3)));
#pragma unroll
            for (int n = 0; n < 8; ++n) {
                int rd = n * 16 + fr;
                short8 vb = *(const short8*)(lvb + ((rd * 64 + ks2 * 32 + fkb * 8) ^ ((rd & 7) << 3)));
                po[n] = MFMA16(pa, vb, po[n]);
            }
        }
    }

    // epilogue: row-sum reduce, normalize, fp16 write
#pragma unroll
    for (int jj = 0; jj < 4; ++jj) {
        float v = lsum[jj];
        v += __shfl_xor(v, 1);
        v += __shfl_xor(v, 2);
        v += __shfl_xor(v, 4);
        v += __shfl_xor(v, 8);
        lsum[jj] = 1.0f / v;
    }
    u16* outz = Sout + (long)z * 131072;
#pragma unroll
    for (int jj = 0; jj < 4; ++jj) {
        int qrow2 = qt * 64 + w * 16 + fkb * 4 + jj;
        int Mo = qrow2 >> 7, r = qrow2 & 127, sw = (r & 7) << 3;
#pragma unroll
        for (int n = 0; n < 8; ++n) {
            int d = n * 16 + fr;
            outz[(long)(Mo * 2 + (d >> 6)) * 8192 + ((r * 64 + (d & 63)) ^ sw)] =
                hbits(po[n][jj] * lsum[jj]);
        }
    }
}

// Final softmax (t=2): raw fp32 scores -> normalized fp32 full row (zeros past causal)
// + fp16 blocked P_s (packed causal: z*589824 + qt*(qt+1)*8192 u16).
__global__ __launch_bounds__(256) void softmaxF(
    float* __restrict__ sc, const float* __restrict__ lb, u16* __restrict__ P_s)
{
    const int row = blockIdx.x;
    const long z = blockIdx.y;
    float* rp = sc + (z * 1024 + row) * 1024;
    const int W = ((row >> 7) + 1) << 7, qt = row >> 7;
    const int tid = threadIdx.x, w = tid >> 6, lane = tid & 63;
    const float sb = 0.08838834764831845f * expf(lb[0]);
    const int c0 = tid * 4;
    const bool act = c0 < W;
    float x0 = -3e38f, x1 = -3e38f, x2 = -3e38f, x3 = -3e38f;
    if (act) {
        float4 v = *reinterpret_cast<const float4*>(rp + c0);
        x0 = (c0 + 0 <= row) ? v.x * sb : -3e38f;
        x1 = (c0 + 1 <= row) ? v.y * sb : -3e38f;
        x2 = (c0 + 2 <= row) ? v.z * sb : -3e38f;
        x3 = (c0 + 3 <= row) ? v.w * sb : -3e38f;
    }
    __shared__ float red[8];
    float mx = fmaxf(fmaxf(x0, x1), fmaxf(x2, x3));
#pragma unroll
    for (int o = 32; o; o >>= 1) mx = fmaxf(mx, __shfl_xor(mx, o));
    if (!lane) red[w] = mx;
    __syncthreads();
    mx = fmaxf(fmaxf(red[0], red[1]), fmaxf(red[2], red[3]));

    float e0 = expf(x0 - mx), e1 = expf(x1 - mx), e2 = expf(x2 - mx), e3 = expf(x3 - mx);
    float sm = e0 + e1 + e2 + e3;
#pragma unroll
    for (int o = 32; o; o >>= 1) sm += __shfl_xor(sm, o);
    if (!lane) red[4 + w] = sm;
    __syncthreads();
    sm = red[4] + red[5] + red[6] + red[7];
    float inv = 1.0f / sm;

    float p0 = e0 * inv, p1 = e1 * inv, p2 = e2 * inv, p3 = e3 * inv;
    float4 o4; o4.x = p0; o4.y = p1; o4.z = p2; o4.w = p3;
    *reinterpret_cast<float4*>(rp + c0) = o4;
    if (act) {
        const int r = row & 127, sw = (r & 7) << 3;
        long idx = z * 589824 + (long)qt * (qt + 1) * 8192 + (long)(c0 >> 6) * 8192
                 + ((r * 64 + (c0 & 63)) ^ sw);
        us4 pw; pw[0] = hbits(p0); pw[1] = hbits(p1); pw[2] = hbits(p2); pw[3] = hbits(p3);
        *(us4*)(P_s + idx) = pw;
    }
}

// Final PV: stateF = P . V (fp16 x fp16), fp16 blocked out [16 Mt][32 Kt]. grid (qt=8, z=32).
__global__ __launch_bounds__(256) void pvfin(
    const u16* __restrict__ P_s, const u16* __restrict__ vT_s, u16* __restrict__ stateF)
{
    const int qt = blockIdx.x, z = blockIdx.y;
    const int b = z >> 4, h = z & 15;
    const int zp = b * 8 + (h >> 1);
    __shared__ u16 LA[8192], LB[8192];
    const int tid = threadIdx.x, w = tid >> 6, lane = tid & 63;
    const int fr = lane & 15, fkb = lane >> 4;
    const int wr = w * 32;

    const char* Pa = (const char*)(P_s + (long)z * 589824 + (long)qt * (qt + 1) * 8192);
    const char* Vz = (const char*)(vT_s + (long)zp * 131072);
    const int nj = 2 * qt + 2;

    f32x4 po[2][8] = {};
#pragma unroll 1
    for (int jsb = 0; jsb < nj; ++jsb) {
        __syncthreads();
#pragma unroll
        for (int i = 0; i < 4; ++i) {
            gload16(Pa + (long)jsb * 16384 + i * 4096 + w * 1024 + lane * 16,
                    (char*)LA + i * 4096 + w * 1024);
            gload16(Vz + (long)jsb * 16384 + i * 4096 + w * 1024 + lane * 16,
                    (char*)LB + i * 4096 + w * 1024);
        }
        __syncthreads();
#pragma unroll
        for (int ks2 = 0; ks2 < 2; ++ks2) {
            short8 pa[2];
#pragma unroll
            for (int m = 0; m < 2; ++m) {
                int r = wr + m * 16 + fr;
                pa[m] = *(const short8*)(LA + ((r * 64 + ks2 * 32 + fkb * 8) ^ ((r & 7) << 3)));
            }
#pragma unroll
            for (int n = 0; n < 8; ++n) {
                int rd = n * 16 + fr;
                short8 vb = *(const short8*)(LB + ((rd * 64 + ks2 * 32 + fkb * 8) ^ ((rd & 7) << 3)));
#pragma unroll
                for (int m = 0; m < 2; ++m)
                    po[m][n] = MFMA16(pa[m], vb, po[m][n]);
            }
        }
    }
    const int Mt = b * 8 + qt;
#pragma unroll
    for (int m = 0; m < 2; ++m)
#pragma unroll
        for (int jj = 0; jj < 4; ++jj) {
            int rl = wr + m * 16 + fkb * 4 + jj, sw = (rl & 7) << 3;
#pragma unroll
            for (int n = 0; n < 8; ++n) {
                int d = n * 16 + fr;
                int Kt = h * 2 + (d >> 6);
                stateF[((long)Mt * 32 + Kt) * 8192 + ((rl * 64 + (d & 63)) ^ sw)] =
                    hbits(po[m][n][jj]);
            }
        }
}

extern "C" void kernel_launch(void* const* d_in, const int* in_sizes, int n_in,
                              void* d_out, int out_size, void* d_ws, size_t ws_size,
                              hipStream_t stream)
{
    const float* hs   = (const float*)d_in[0];
    const float* cosb = (const float*)d_in[1];
    const float* sinb = (const float*)d_in[2];
    const float* Wq   = (const float*)d_in[4];
    const float* Wk   = (const float*)d_in[5];
    const float* Wv   = (const float*)d_in[6];
    const float* Wo   = (const float*)d_in[7];
    const float* qw   = (const float*)d_in[8];
    const float* kw   = (const float*)d_in[9];
    const float* lb   = (const float*)d_in[10];

    float* out  = (float*)d_out;
    float* attn = out + 4194304;

    char* ws = (char*)d_ws;
    // byte layout (total 125,829,120 <= known-available 142.6 MB)
    u16*   hs_c     = (u16*)(ws);                    // 8.4 MB
    u16*   Wqkv_c   = (u16*)(ws + 8388608L);         // 16.8 MB
    u16*   Wo_c     = (u16*)(ws + 25165824L);        // 8.4 MB
    float* qkv      = (float*)(ws + 33554432L);      // 33.5 MB, dead after epi
    u16*   state2_s = (u16*)(ws + 33554432L);        // alias (8.4 MB)
    u16*   stateF_s = (u16*)(ws + 41943040L);        // alias (8.4 MB)
    u16*   state_s  = (u16*)(ws + 67108864L);        // 8.4 MB
    u16*   k_s      = (u16*)(ws + 75497472L);        // 4.2 MB
    u16*   kT_s     = (u16*)(ws + 79691776L);        // 4.2 MB
    u16*   vT_s     = (u16*)(ws + 83886080L);        // 4.2 MB
    u16*   P_s      = (u16*)(ws + 88080384L);        // 37.7 MB

    cvtk<<<2048, 256, 0, stream>>>(hs, hs_c);
    cvt3<<<4096, 256, 0, stream>>>(Wq, Wk, Wv, Wqkv_c);
    cvtk<<<2048, 256, 0, stream>>>(Wo, Wo_c);

    // qkv = hs . Wqkv^T  (M=2048, N=4096, K=2048)
    gemmk<0><<<dim3(32, 16, 1), 256, 0, stream>>>(hs_c, Wqkv_c, qkv, 32, 1,
        0L, 0L, 1, 262144L,  0L, 0L, 1, 262144L,  0L, 0L, 1, 4096L);

    qkv_epi<<<2048, 256, 0, stream>>>(qkv, cosb, sinb, qw, kw, state_s, k_s, kT_s, vT_s);

    // t = 0, 1 fused
    hopstep<<<512, 256, 0, stream>>>(state_s, k_s, kT_s, lb, state2_s);
    hopstep<<<512, 256, 0, stream>>>(state2_s, k_s, kT_s, lb, state_s);

    // t = 2: raw scores (causal blocks) -> exact softmax (fp32 attn + fp16 P) -> PV
    gemmk<1><<<dim3(8, 8, 32), 256, 0, stream>>>(state_s, k_s, attn, 2, 16,
        2097152L, 131072L, 1, 16384L,
        1048576L, 131072L, 2, 16384L,
        16777216L, 1048576L, 1, 1024L);
    softmaxF<<<dim3(1024, 32), 256, 0, stream>>>(attn, lb, P_s);
    pvfin<<<dim3(8, 32), 256, 0, stream>>>(P_s, vT_s, stateF_s);

    // out = stateF . Wo^T  (M=2048, N=2048, K=2048)
    gemmk<0><<<dim3(16, 16, 1), 256, 0, stream>>>(stateF_s, Wo_c, out, 32, 1,
        0L, 0L, 1, 262144L,  0L, 0L, 1, 262144L,  0L, 0L, 1, 2048L);
}

// Round 6
// 292.930 us; speedup vs baseline: 3.1772x; 1.0777x over previous
//
#include <hip/hip_runtime.h>

#define DEVI __device__ __forceinline__

typedef __attribute__((ext_vector_type(8))) short short8;
typedef __attribute__((ext_vector_type(4))) float f32x4;
typedef unsigned short u16;
typedef __attribute__((ext_vector_type(4))) u16 us4;
typedef __attribute__((ext_vector_type(8))) u16 us8;

#define MFMA16(a, b, c) __builtin_amdgcn_mfma_f32_16x16x32_f16(a, b, c, 0, 0, 0)

DEVI u16 hbits(float x) {
    union { _Float16 h; u16 u; } cv;
    cv.h = (_Float16)x;
    return cv.u;
}
DEVI float h2f(u16 u) {
    union { u16 u; _Float16 h; } cv;
    cv.u = u;
    return (float)cv.h;
}

DEVI void gload16(const void* g, void* l) {
    __builtin_amdgcn_global_load_lds(
        (const __attribute__((address_space(1))) unsigned int*)g,
        (__attribute__((address_space(3))) unsigned int*)l, 16, 0, 0);
}

// ---- layout ----
// fp16 block: [128 rows][64 k] as u16[8192] (16 KB): idx = (r*64 + k) ^ ((r&7)<<3)
// Buffers are [Mt][Kt] grids of blocks. P tiles are 64x64: idx = (r*64+c) ^ ((r&7)<<3).

// All fp32->fp16 blocked conversions in one kernel. rows: 0-2047 hs, 2048-6143 Wq|Wk|Wv, 6144-8191 Wo.
__global__ __launch_bounds__(256) void cvtall(
    const float* __restrict__ hs, const float* __restrict__ Wq, const float* __restrict__ Wk,
    const float* __restrict__ Wv, const float* __restrict__ Wo,
    u16* __restrict__ hs_c, u16* __restrict__ Wqkv_c, u16* __restrict__ Wo_c)
{
    const long t = (long)blockIdx.x * 256 + threadIdx.x;
    const int row = (int)(t >> 8), kg = (int)(t & 255);
    const int k0 = kg << 3;
    const float* src; u16* dst; int orow;
    if (row < 2048)      { src = hs + (long)row * 2048 + k0;          dst = hs_c;   orow = row; }
    else if (row < 4096) { src = Wq + (long)(row - 2048) * 2048 + k0; dst = Wqkv_c; orow = row - 2048; }
    else if (row < 5120) { src = Wk + (long)(row - 4096) * 2048 + k0; dst = Wqkv_c; orow = row - 2048; }
    else if (row < 6144) { src = Wv + (long)(row - 5120) * 2048 + k0; dst = Wqkv_c; orow = row - 2048; }
    else                 { src = Wo + (long)(row - 6144) * 2048 + k0; dst = Wo_c;   orow = row - 6144; }
    float4 a = *(const float4*)src, b = *(const float4*)(src + 4);
    float f[8] = {a.x, a.y, a.z, a.w, b.x, b.y, b.z, b.w};
    us8 h;
#pragma unroll
    for (int j = 0; j < 8; ++j) h[j] = hbits(f[j]);
    const int Kt = k0 >> 6, c = k0 & 63, r = orow & 127, Rt = orow >> 7, sw = (r & 7) << 3;
    *(us8*)(dst + ((long)Rt * 32 + Kt) * 8192 + ((r * 64 + c) ^ sw)) = h;
}

// 128x128-tile GEMM, C = A * B^T (fp16 blocked operands, fp32 out), BK=64, double-buffered LDS.
__global__ __launch_bounds__(256) void gemmk(
    const u16* __restrict__ Ap, const u16* __restrict__ Bp, float* __restrict__ Cp,
    int nKt, long ldc)
{
    const int m0 = blockIdx.y * 128, n0 = blockIdx.x * 128;
    __shared__ u16 LA[2][8192], LB[2][8192];
    const int tid = threadIdx.x, w = tid >> 6, lane = tid & 63;
    const int wr = (w >> 1) * 64, wc = (w & 1) * 64, fr = lane & 15, fkb = lane >> 4;

    const u16* Ab = Ap + (long)(m0 >> 7) * nKt * 8192;
    const u16* Bb = Bp + (long)(n0 >> 7) * nKt * 8192;

    auto stage = [&](int kt, int buf) {
        const char* sa = (const char*)(Ab + (long)kt * 8192);
        const char* sb = (const char*)(Bb + (long)kt * 8192);
#pragma unroll
        for (int i = 0; i < 4; ++i) {
            gload16(sa + i * 4096 + w * 1024 + lane * 16, (char*)LA[buf] + i * 4096 + w * 1024);
            gload16(sb + i * 4096 + w * 1024 + lane * 16, (char*)LB[buf] + i * 4096 + w * 1024);
        }
    };

    f32x4 acc[4][4] = {};
    stage(0, 0);
    int cur = 0;
    for (int kt = 0; kt < nKt; ++kt) {
        __syncthreads();                       // buf[cur] staged; prior reads of buf[cur^1] done
        if (kt + 1 < nKt) stage(kt + 1, cur ^ 1);

        const u16* la = LA[cur];
        const u16* lb = LB[cur];
        short8 av[4][2], bv[4][2];
#pragma unroll
        for (int m = 0; m < 4; ++m) {
            int r = wr + m * 16 + fr, sw = (r & 7) << 3;
#pragma unroll
            for (int ks = 0; ks < 2; ++ks)
                av[m][ks] = *(const short8*)(la + ((r * 64 + ks * 32 + fkb * 8) ^ sw));
        }
#pragma unroll
        for (int n = 0; n < 4; ++n) {
            int r = wc + n * 16 + fr, sw = (r & 7) << 3;
#pragma unroll
            for (int ks = 0; ks < 2; ++ks)
                bv[n][ks] = *(const short8*)(lb + ((r * 64 + ks * 32 + fkb * 8) ^ sw));
        }
#pragma unroll
        for (int ks = 0; ks < 2; ++ks)
#pragma unroll
            for (int m = 0; m < 4; ++m)
#pragma unroll
                for (int n = 0; n < 4; ++n)
                    acc[m][n] = MFMA16(av[m][ks], bv[n][ks], acc[m][n]);
        cur ^= 1;
    }

#pragma unroll
    for (int m = 0; m < 4; ++m)
#pragma unroll
        for (int j = 0; j < 4; ++j) {
            long row = m0 + wr + m * 16 + fkb * 4 + j;
#pragma unroll
            for (int n = 0; n < 4; ++n)
                Cp[row * ldc + n0 + wc + n * 16 + fr] = acc[m][n][j];
        }
}

// RMSNorm + RoPE epilogue (reads fp32 qkv). Writes fp16 blocked:
// state_s [z][8 Mt][2 Kt], k_s [zp][8 Mt][2 Kt], kT_s/vT_s [zp][16 sblk][128 d][64 s].
__global__ __launch_bounds__(256) void qkv_epi(
    const float* __restrict__ qkv, const float* __restrict__ cosb, const float* __restrict__ sinb,
    const float* __restrict__ qw, const float* __restrict__ kw,
    u16* __restrict__ state_s, u16* __restrict__ k_s,
    u16* __restrict__ kT_s, u16* __restrict__ vT_s)
{
    const int bs = blockIdx.x, b = bs >> 10, s = bs & 1023;
    const float* row = qkv + (long)bs * 4096;
    const int w = threadIdx.x >> 6, lane = threadIdx.x & 63;
    const float clo = cosb[(long)bs * 128 + lane], chi = cosb[(long)bs * 128 + 64 + lane];
    const float slo = sinb[(long)bs * 128 + lane], shi = sinb[(long)bs * 128 + 64 + lane];
    const int Mt = s >> 7, r = s & 127, sw = (r & 7) << 3;
    const float qwl = qw[lane], qwh = qw[lane + 64], kwl = kw[lane], kwh = kw[lane + 64];
    const int swl = (lane & 7) << 3;

    for (int h = w; h < 16; h += 4) {
        float xlo = row[h * 128 + lane], xhi = row[h * 128 + 64 + lane];
        float ss = xlo * xlo + xhi * xhi;
#pragma unroll
        for (int o = 32; o; o >>= 1) ss += __shfl_xor(ss, o);
        float rr = 1.0f / sqrtf(ss * (1.0f / 128.0f) + 1e-6f);
        float ylo = xlo * rr * qwl, yhi = xhi * rr * qwh;
        float olo = ylo * clo - yhi * slo;
        float ohi = yhi * chi + ylo * shi;
        u16* dst = state_s + (long)(b * 16 + h) * 131072 + (long)Mt * 16384;
        dst[(r * 64 + lane) ^ sw] = hbits(olo);
        dst[8192 + ((r * 64 + lane) ^ sw)] = hbits(ohi);
    }
    for (int kv = w; kv < 8; kv += 4) {
        float xlo = row[2048 + kv * 128 + lane], xhi = row[2048 + kv * 128 + 64 + lane];
        float ss = xlo * xlo + xhi * xhi;
#pragma unroll
        for (int o = 32; o; o >>= 1) ss += __shfl_xor(ss, o);
        float rr = 1.0f / sqrtf(ss * (1.0f / 128.0f) + 1e-6f);
        float ylo = xlo * rr * kwl, yhi = xhi * rr * kwh;
        float olo = ylo * clo - yhi * slo;
        float ohi = yhi * chi + ylo * shi;
        const long zp = (long)(b * 8 + kv);
        u16* dst = k_s + zp * 131072 + (long)Mt * 16384;
        dst[(r * 64 + lane) ^ sw] = hbits(olo);
        dst[8192 + ((r * 64 + lane) ^ sw)] = hbits(ohi);
        u16* dT = kT_s + zp * 131072 + (long)(s >> 6) * 8192;
        const int c = s & 63;
        dT[(lane * 64 + c) ^ swl] = hbits(olo);
        dT[((lane + 64) * 64 + c) ^ swl] = hbits(ohi);
    }
    for (int kv = w; kv < 8; kv += 4) {
        float xlo = row[3072 + kv * 128 + lane], xhi = row[3072 + kv * 128 + 64 + lane];
        u16* dT = vT_s + (long)(b * 8 + kv) * 131072 + (long)(s >> 6) * 8192;
        const int c = s & 63;
        dT[(lane * 64 + c) ^ swl] = hbits(xlo);
        dT[((lane + 64) * 64 + c) ^ swl] = hbits(xhi);
    }
}

// Fused Hopfield step. grid 512 blocks: z = bid&31, qt = balance(bid>>5) in 0..15 (64-row q-tile).
// Shifted exp (mathematically exact softmax after normalization); lsum accumulates
// fp16-ROUNDED p so downstream normalization is an exact softmax of perturbed logits.
// STEP<2: PV source = kT, write normalized state to Sout (state layout).
// STEP=2: PV source = vT, write stateF layout + unnormalized fp16 P tiles + 1/lsum.
template<int STEP>
__global__ __launch_bounds__(256) void hopstep(
    const u16* __restrict__ Sin, const u16* __restrict__ Ks,
    const u16* __restrict__ PVs, const float* __restrict__ lb,
    u16* __restrict__ Sout, u16* __restrict__ P_s, float* __restrict__ lsumb)
{
    const int bid = blockIdx.x;
    const int z = bid & 31;
    const int g = bid >> 5;
    const int qt = (g < 8) ? g : 23 - g;
    const int b = z >> 4, h = z & 15;
    const int zp = b * 8 + (h >> 1);
    const float sb = 0.08838834764831845f * __expf(lb[0]);

    __shared__ u16 LK[8192];      // K j-tile [2 Kt][64][64]  (16 KB)
    __shared__ u16 LV[2][8192];   // kT/vT s-block double buffer (2 x 16 KB)
    __shared__ u16 LP[4096];      // P tile 64x64 fp16 (8 KB)

    const int tid = threadIdx.x, w = tid >> 6, lane = tid & 63;
    const int fr = lane & 15, fkb = lane >> 4;

    // Q into registers
    const int qrow = qt * 64 + w * 16 + fr;
    const int qMt = qrow >> 7, qr = qrow & 127, qsw = (qr & 7) << 3;
    const u16* Qg = Sin + (long)z * 131072 + (long)qMt * 16384;
    short8 qv[4];
#pragma unroll
    for (int ks = 0; ks < 4; ++ks)
        qv[ks] = *(const short8*)(Qg + (ks >> 1) * 8192 + ((qr * 64 + (ks & 1) * 32 + fkb * 8) ^ qsw));

    const char* Kzb = (const char*)(Ks + (long)zp * 131072);
    const char* Vz  = (const char*)(PVs + (long)zp * 131072);
    const int jend = qt + 1;

    f32x4 po[8] = {};
    float lsum[4] = {0.f, 0.f, 0.f, 0.f};

    // prologue: stage K(jt=0) and V(jt=0)
#pragma unroll
    for (int i = 0; i < 4; ++i) {
        gload16(Kzb + (i >> 1) * 16384 + (i & 1) * 4096 + w * 1024 + lane * 16,
                (char*)LK + i * 4096 + w * 1024);
        gload16(Vz + i * 4096 + w * 1024 + lane * 16, (char*)LV[0] + i * 4096 + w * 1024);
    }

#pragma unroll 1
    for (int jt = 0; jt < jend; ++jt) {
        __syncthreads();   // LK(jt), LV[jt&1] ready; previous LP reads done

        const bool diag = (jt == qt);
        const int nmax = diag ? (w + 1) : 4;

        f32x4 ps[4] = {};
#pragma unroll 1
        for (int n = 0; n < nmax; ++n) {
            int rj = n * 16 + fr, swj = (rj & 7) << 3;
#pragma unroll
            for (int ks = 0; ks < 4; ++ks) {
                short8 bk = *(const short8*)(LK + (ks >> 1) * 4096 +
                                             ((rj * 64 + (ks & 1) * 32 + fkb * 8) ^ swj));
                ps[n] = MFMA16(qv[ks], bk, ps[n]);
            }
        }

        // shifted exp + fp16 rounding; lsum uses the ROUNDED value (consistent normalization)
        const int qloc = w * 16 + fkb * 4;
#pragma unroll
        for (int n = 0; n < 4; ++n) {
            int jcol = n * 16 + fr;
#pragma unroll
            for (int jj = 0; jj < 4; ++jj) {
                float p = 0.f;
                if (n < nmax) {
                    bool msk = diag && (jcol > qloc + jj);
                    p = msk ? 0.f : __expf(ps[n][jj] * sb - 4.0f);
                }
                u16 ph = hbits(p);
                lsum[jj] += h2f(ph);
                int rq = qloc + jj;
                LP[(rq * 64 + jcol) ^ ((rq & 7) << 3)] = ph;
            }
        }

        __syncthreads();   // LP visible; LK reads complete

        if (jt + 1 < jend) {
            const int jn = jt + 1;
#pragma unroll
            for (int i = 0; i < 4; ++i) {
                gload16(Kzb + (long)((jn >> 1) * 2 + (i >> 1)) * 16384 + (jn & 1) * 8192 +
                            (i & 1) * 4096 + w * 1024 + lane * 16,
                        (char*)LK + i * 4096 + w * 1024);
                gload16(Vz + (long)jn * 16384 + i * 4096 + w * 1024 + lane * 16,
                        (char*)LV[jn & 1] + i * 4096 + w * 1024);
            }
        }

        if (STEP == 2) {
            // coalesced copy of the raw (swizzled) LP tile to packed-causal P_s
            u16* pd = P_s + (long)z * 557056 + 2048L * qt * (qt + 1) + (long)jt * 4096;
            *(us8*)(pd + tid * 16)     = *(const us8*)(LP + tid * 16);
            *(us8*)(pd + tid * 16 + 8) = *(const us8*)(LP + tid * 16 + 8);
        }

        // PV
        const u16* lvb = LV[jt & 1];
        const int rq = w * 16 + fr;
#pragma unroll
        for (int ks2 = 0; ks2 < 2; ++ks2) {
            short8 pa = *(const short8*)(LP + ((rq * 64 + ks2 * 32 + fkb * 8) ^ ((rq & 7) << 3)));
#pragma unroll
            for (int n = 0; n < 8; ++n) {
                int rd = n * 16 + fr;
                short8 vb = *(const short8*)(lvb + ((rd * 64 + ks2 * 32 + fkb * 8) ^ ((rd & 7) << 3)));
                po[n] = MFMA16(pa, vb, po[n]);
            }
        }
    }

    // epilogue: row-sum reduce, normalize, write
#pragma unroll
    for (int jj = 0; jj < 4; ++jj) {
        float v = lsum[jj];
        v += __shfl_xor(v, 1);
        v += __shfl_xor(v, 2);
        v += __shfl_xor(v, 4);
        v += __shfl_xor(v, 8);
        lsum[jj] = 1.0f / v;
    }
    if (STEP == 2) {
        if (fr == 0) {
#pragma unroll
            for (int jj = 0; jj < 4; ++jj)
                lsumb[(long)z * 1024 + qt * 64 + w * 16 + fkb * 4 + jj] = lsum[jj];
        }
#pragma unroll
        for (int jj = 0; jj < 4; ++jj) {
            int qr2 = qt * 64 + w * 16 + fkb * 4 + jj;
            int Mtg = b * 8 + (qr2 >> 7), r = qr2 & 127, sw = (r & 7) << 3;
#pragma unroll
            for (int n = 0; n < 8; ++n) {
                int d = n * 16 + fr;
                int Kt = h * 2 + (d >> 6);
                Sout[((long)Mtg * 32 + Kt) * 8192 + ((r * 64 + (d & 63)) ^ sw)] =
                    hbits(po[n][jj] * lsum[jj]);
            }
        }
    } else {
        u16* outz = Sout + (long)z * 131072;
#pragma unroll
        for (int jj = 0; jj < 4; ++jj) {
            int qr2 = qt * 64 + w * 16 + fkb * 4 + jj;
            int Mo = qr2 >> 7, r = qr2 & 127, sw = (r & 7) << 3;
#pragma unroll
            for (int n = 0; n < 8; ++n) {
                int d = n * 16 + fr;
                outz[(long)(Mo * 2 + (d >> 6)) * 8192 + ((r * 64 + (d & 63)) ^ sw)] =
                    hbits(po[n][jj] * lsum[jj]);
            }
        }
    }
}

// Normalize packed-causal fp16 P -> full-width fp32 attn rows (exact zeros past causal).
__global__ __launch_bounds__(256) void softmaxN(
    const u16* __restrict__ P_s, const float* __restrict__ lsumb, float* __restrict__ attn)
{
    const int row = blockIdx.x;
    const long z = blockIdx.y;
    const int qt = row >> 6, r = row & 63, sw = (r & 7) << 3;
    const float inv = lsumb[z * 1024 + row];
    const int W = (qt + 1) << 6;
    const u16* Pz = P_s + z * 557056 + 2048L * qt * (qt + 1);
    float* rp = attn + (z * 1024 + row) * 1024;
    const int c0 = threadIdx.x * 4;
    float4 o = {0.f, 0.f, 0.f, 0.f};
    if (c0 < W) {
        us4 pv = *(const us4*)(Pz + (long)(c0 >> 6) * 4096 + ((r * 64 + (c0 & 63)) ^ sw));
        o.x = h2f(pv[0]) * inv;
        o.y = h2f(pv[1]) * inv;
        o.z = h2f(pv[2]) * inv;
        o.w = h2f(pv[3]) * inv;
    }
    *(float4*)(rp + c0) = o;
}

extern "C" void kernel_launch(void* const* d_in, const int* in_sizes, int n_in,
                              void* d_out, int out_size, void* d_ws, size_t ws_size,
                              hipStream_t stream)
{
    const float* hs   = (const float*)d_in[0];
    const float* cosb = (const float*)d_in[1];
    const float* sinb = (const float*)d_in[2];
    const float* Wq   = (const float*)d_in[4];
    const float* Wk   = (const float*)d_in[5];
    const float* Wv   = (const float*)d_in[6];
    const float* Wo   = (const float*)d_in[7];
    const float* qw   = (const float*)d_in[8];
    const float* kw   = (const float*)d_in[9];
    const float* lb   = (const float*)d_in[10];

    float* out  = (float*)d_out;
    float* attn = out + 4194304;

    char* ws = (char*)d_ws;
    u16*   hs_c     = (u16*)(ws);                    // 8.4 MB
    u16*   Wqkv_c   = (u16*)(ws + 8388608L);         // 16.8 MB
    u16*   Wo_c     = (u16*)(ws + 25165824L);        // 8.4 MB
    float* qkv      = (float*)(ws + 33554432L);      // 33.5 MB, dead after epi
    u16*   state2_s = (u16*)(ws + 33554432L);        // alias (8.4 MB)
    u16*   stateF_s = (u16*)(ws + 41943040L);        // alias (8.4 MB)
    u16*   state_s  = (u16*)(ws + 67108864L);        // 8.4 MB
    u16*   k_s      = (u16*)(ws + 75497472L);        // 4.2 MB
    u16*   kT_s     = (u16*)(ws + 79691776L);        // 4.2 MB
    u16*   vT_s     = (u16*)(ws + 83886080L);        // 4.2 MB
    u16*   P_s      = (u16*)(ws + 88080384L);        // 35.7 MB (packed causal)
    float* lsumb    = (float*)(ws + 123731968L);     // 131 KB

    cvtall<<<8192, 256, 0, stream>>>(hs, Wq, Wk, Wv, Wo, hs_c, Wqkv_c, Wo_c);

    // qkv = hs . Wqkv^T  (M=2048, N=4096, K=2048)
    gemmk<<<dim3(32, 16), 256, 0, stream>>>(hs_c, Wqkv_c, qkv, 32, 4096L);

    qkv_epi<<<2048, 256, 0, stream>>>(qkv, cosb, sinb, qw, kw, state_s, k_s, kT_s, vT_s);

    // t = 0, 1 fused
    hopstep<0><<<512, 256, 0, stream>>>(state_s, k_s, kT_s, lb, state2_s, nullptr, nullptr);
    hopstep<0><<<512, 256, 0, stream>>>(state2_s, k_s, kT_s, lb, state_s, nullptr, nullptr);

    // t = 2 fused: P (unnormalized fp16) + 1/sum + stateF
    hopstep<2><<<512, 256, 0, stream>>>(state_s, k_s, vT_s, lb, stateF_s, P_s, lsumb);

    // attn = P / sum (full width, exact zeros past causal)
    softmaxN<<<dim3(1024, 32), 256, 0, stream>>>(P_s, lsumb, attn);

    // out = stateF . Wo^T  (M=2048, N=2048, K=2048)
    gemmk<<<dim3(16, 16), 256, 0, stream>>>(stateF_s, Wo_c, out, 32, 2048L);
}